// Round 24
// baseline (216.902 us; speedup 1.0000x reference)
//
#include <hip/hip_runtime.h>
#include <type_traits>

#define S_LEN 2048
#define BATCH 2
#define EDIM  2048
#define NH    16
#define NKV   4
#define HDIM  128
#define QKVD  3072
// ATT_SCALE * log2(e): folded into Q at conv_rope time -> scores in log2 domain
#define QSCALE 0.12751579107188777f

typedef __attribute__((ext_vector_type(8))) short short8;
typedef __attribute__((ext_vector_type(4))) float f32x4;

__device__ __forceinline__ ushort f2bf(float f) {
  union { float f; unsigned u; } un; un.f = f;
  unsigned u = un.u + 0x7fffu + ((un.u >> 16) & 1u);
  return (ushort)(u >> 16);
}
__device__ __forceinline__ float bf2f(ushort h) {
  union { unsigned u; float f; } un; un.u = ((unsigned)h) << 16;
  return un.f;
}
__device__ __forceinline__ unsigned cvt_pk_bf16(float lo, float hi) {
  unsigned r;
  asm("v_cvt_pk_bf16_f32 %0, %1, %2" : "=v"(r) : "v"(lo), "v"(hi));
  return r;
}
__device__ __forceinline__ float fexp2(float x) { return __builtin_amdgcn_exp2f(x); }

__device__ __forceinline__ void load_lds16(const void* g, void* l) {
  __builtin_amdgcn_global_load_lds((const __attribute__((address_space(1))) void*)g,
                                   (__attribute__((address_space(3))) void*)l,
                                   16, 0, 0);
}

// ---------------- fused f32 -> bf16 casts (x, w_in, w_out) ----------------
__global__ __launch_bounds__(256) void cast3(const float* __restrict__ a,
                                             const float* __restrict__ b,
                                             const float* __restrict__ c,
                                             ushort* __restrict__ oa,
                                             ushort* __restrict__ ob,
                                             ushort* __restrict__ oc) {
  int i = blockIdx.x * 256 + threadIdx.x;       // [0, 4718592)
  const float* s; ushort* d; int j;
  if (i < 2097152)      { s = a; d = oa; j = i; }
  else if (i < 3670016) { s = b; d = ob; j = i - 2097152; }
  else                  { s = c; d = oc; j = i - 3670016; }
  float4 v = ((const float4*)s)[j];
  ushort4 o;
  o.x = f2bf(v.x); o.y = f2bf(v.y); o.z = f2bf(v.z); o.w = f2bf(v.w);
  ((ushort4*)d)[j] = o;
}

// ---------------- conv weight transpose: cw[c][j] -> cwT[j][c] (4 x 3072 f32) ----------------
__global__ __launch_bounds__(256) void transpose_cw(const float* __restrict__ cw,
                                                    float* __restrict__ cwT) {
  int i = blockIdx.x * 256 + threadIdx.x;       // [0, 12288)
  int c = i >> 2, j = i & 3;
  cwT[j * QKVD + c] = cw[i];
}

// ---------------- RoPE cos/sin table: [S][64] ----------------
__global__ __launch_bounds__(256) void rope_table(float* __restrict__ cosT,
                                                  float* __restrict__ sinT) {
  int i = blockIdx.x * 256 + threadIdx.x;   // S*64 total
  int s = i >> 6, d = i & 63;
  float inv = expf(-(float)d * 0.14391156831212787f);   // 10000^(-d/64)
  float f = (float)s * inv;
  float sv, cv;
  sincosf(f, &sv, &cv);
  cosT[i] = cv;
  sinT[i] = sv;
}

// ---------------- 128x128 ring-4 bf16 NT GEMM (r22-proven) ----------------
template <bool OBF>
__global__ __launch_bounds__(256, 2) void gemm128(
    const ushort* __restrict__ A, const ushort* __restrict__ Bt,
    const float* __restrict__ bias, void* __restrict__ Cv,
    int M, int N, int K) {
  __shared__ __align__(16) ushort LA[4][4096];   // [slot][128 rows x 32 cols]
  __shared__ __align__(16) ushort LB[4][4096];
  const int tid = threadIdx.x;
  const int wid = tid >> 6, lane = tid & 63;
  const int l15 = lane & 15, lg = lane >> 4;
  const int wr = wid >> 1, wc = wid & 1;
  const int nTn = N >> 7;
  const int cpx = gridDim.x >> 3;                 // grid divisible by 8
  const int swz = ((int)blockIdx.x & 7) * cpx + ((int)blockIdx.x >> 3);
  const int m0 = (swz / nTn) * 128, n0 = (swz % nTn) * 128;
  const ushort* Ag = A + (size_t)m0 * K;
  const ushort* Bg = Bt + (size_t)n0 * K;
  const int coff = (lg ^ ((l15 >> 1) & 3)) * 8;
  const int abase = (wr * 64 + l15) * 32 + coff;
  const int bbase = (wc * 64 + l15) * 32 + coff;
  const int nk = K >> 5;

  f32x4 acc[4][4] = {};

  auto stage_one = [&](const ushort* G, ushort* Ls, int k0) {
#pragma unroll
    for (int i = 0; i < 2; ++i) {
      const int c = i * 256 + tid;                // chunk 0..511 (16B each)
      const int row = c >> 2, cc = c & 3;
      const int scc = cc ^ ((row >> 1) & 3);      // inverse-swizzle the SOURCE
      load_lds16(G + (size_t)row * K + k0 + scc * 8,
                 Ls + (i * 256 + wid * 64) * 8);
    }
  };

#pragma unroll
  for (int t = 0; t < 3; ++t) {
    stage_one(Ag, LA[t], t * 32);
    stage_one(Bg, LB[t], t * 32);
  }
  asm volatile("s_waitcnt vmcnt(8)" ::: "memory");
  __builtin_amdgcn_s_barrier();

  auto ktile = [&](auto VMC, auto STG, int t) {
    constexpr int VM = decltype(VMC)::value;
    constexpr bool STAGE = decltype(STG)::value;
    const int slot = t & 3;
    const ushort* Las = LA[slot];
    const ushort* Lbs = LB[slot];
    short8 afr[4], bfr[4];
#pragma unroll
    for (int n = 0; n < 4; ++n) bfr[n] = *(const short8*)&Lbs[bbase + n * 512];
#pragma unroll
    for (int m = 0; m < 4; ++m) afr[m] = *(const short8*)&Las[abase + m * 512];
    if constexpr (STAGE) {
      stage_one(Ag, LA[(t + 3) & 3], (t + 3) * 32);
      stage_one(Bg, LB[(t + 3) & 3], (t + 3) * 32);
    }
    __builtin_amdgcn_s_setprio(1);
#pragma unroll
    for (int m = 0; m < 4; ++m)
#pragma unroll
      for (int n = 0; n < 4; ++n)
        acc[m][n] = __builtin_amdgcn_mfma_f32_16x16x32_bf16(afr[m], bfr[n], acc[m][n], 0, 0, 0);
    __builtin_amdgcn_s_setprio(0);
    if constexpr (VM == 8)      asm volatile("s_waitcnt vmcnt(8)" ::: "memory");
    else if constexpr (VM == 4) asm volatile("s_waitcnt vmcnt(4)" ::: "memory");
    else if constexpr (VM == 0) asm volatile("s_waitcnt vmcnt(0)" ::: "memory");
    __builtin_amdgcn_s_barrier();
  };

  using tru = std::integral_constant<bool, true>;
  using fal = std::integral_constant<bool, false>;
  for (int t = 0; t + 3 < nk; ++t)
    ktile(std::integral_constant<int, 8>{}, tru{}, t);
  ktile(std::integral_constant<int, 4>{}, fal{}, nk - 3);
  ktile(std::integral_constant<int, 0>{}, fal{}, nk - 2);
  ktile(std::integral_constant<int, -1>{}, fal{}, nk - 1);

#pragma unroll
  for (int m = 0; m < 4; ++m)
#pragma unroll
    for (int n = 0; n < 4; ++n) {
      const int col = n0 + wc * 64 + n * 16 + l15;
      const float bv = bias[col];
#pragma unroll
      for (int r = 0; r < 4; ++r) {
        const int row = m0 + wr * 64 + m * 16 + lg * 4 + r;
        if constexpr (OBF)
          ((ushort*)Cv)[(size_t)row * N + col] = f2bf(acc[m][n][r] + bv);
        else
          ((float*)Cv)[(size_t)row * N + col] = acc[m][n][r] + bv;
      }
    }
}

// ---------------- 256x256 ring-4 bf16 NT GEMM, ONE barrier per K-tile (r17-proven) ----------------
template <bool OBF>
__global__ __launch_bounds__(512, 2) void gemm256(
    const ushort* __restrict__ A, const ushort* __restrict__ Bt,
    const float* __restrict__ bias, void* __restrict__ Cv,
    int M, int N, int K) {
  __shared__ __align__(16) ushort LA[4][8192];   // [slot][256 rows x 32 cols]
  __shared__ __align__(16) ushort LB[4][8192];
  const int tid = threadIdx.x;
  const int wid = tid >> 6, lane = tid & 63;
  const int l15 = lane & 15, lg = lane >> 4;
  const int wr = wid >> 2, wc = wid & 3;
  const int nTn = N >> 8;
  const int cpx = gridDim.x >> 3;                 // grid divisible by 8
  const int swz = ((int)blockIdx.x & 7) * cpx + ((int)blockIdx.x >> 3);
  const int m0 = (swz / nTn) * 256, n0 = (swz % nTn) * 256;
  const ushort* Ag = A + (size_t)m0 * K;
  const ushort* Bg = Bt + (size_t)n0 * K;
  const int coff = (lg ^ ((l15 >> 1) & 3)) * 8;
  const int abase = (wr * 128 + l15) * 32 + coff;
  const int bbase = (wc * 64 + l15) * 32 + coff;
  const int nk = K >> 5;

  f32x4 acc[8][4] = {};

  auto stage_one = [&](const ushort* G, ushort* Ls, int k0) {
#pragma unroll
    for (int i = 0; i < 2; ++i) {
      const int c = i * 512 + tid;                // chunk 0..1023
      const int row = c >> 2, cc = c & 3;
      const int scc = cc ^ ((row >> 1) & 3);      // inverse-swizzle the SOURCE
      load_lds16(G + (size_t)row * K + k0 + scc * 8,
                 Ls + (i * 512 + wid * 64) * 8);
    }
  };

#pragma unroll
  for (int t = 0; t < 3; ++t) {
    stage_one(Ag, LA[t], t * 32);
    stage_one(Bg, LB[t], t * 32);
  }
  asm volatile("s_waitcnt vmcnt(8)" ::: "memory");
  __builtin_amdgcn_s_barrier();

  auto ktile = [&](auto VMC, auto STG, int t) {
    constexpr int VM = decltype(VMC)::value;
    constexpr bool STAGE = decltype(STG)::value;
    const int slot = t & 3;
    const ushort* Las = LA[slot];
    const ushort* Lbs = LB[slot];
    short8 afr[8], bfr[4];
#pragma unroll
    for (int n = 0; n < 4; ++n) bfr[n] = *(const short8*)&Lbs[bbase + n * 512];
#pragma unroll
    for (int m = 0; m < 8; ++m) afr[m] = *(const short8*)&Las[abase + m * 512];
    if constexpr (STAGE) {
      stage_one(Ag, LA[(t + 3) & 3], (t + 3) * 32);
      stage_one(Bg, LB[(t + 3) & 3], (t + 3) * 32);
    }
    __builtin_amdgcn_s_setprio(1);
#pragma unroll
    for (int m = 0; m < 8; ++m)
#pragma unroll
      for (int n = 0; n < 4; ++n)
        acc[m][n] = __builtin_amdgcn_mfma_f32_16x16x32_bf16(afr[m], bfr[n], acc[m][n], 0, 0, 0);
    __builtin_amdgcn_s_setprio(0);
    if constexpr (VM == 8)      asm volatile("s_waitcnt vmcnt(8)" ::: "memory");
    else if constexpr (VM == 4) asm volatile("s_waitcnt vmcnt(4)" ::: "memory");
    else if constexpr (VM == 0) asm volatile("s_waitcnt vmcnt(0)" ::: "memory");
    __builtin_amdgcn_s_barrier();
  };

  using tru = std::integral_constant<bool, true>;
  using fal = std::integral_constant<bool, false>;
  for (int t = 0; t + 3 < nk; ++t)
    ktile(std::integral_constant<int, 8>{}, tru{}, t);
  ktile(std::integral_constant<int, 4>{}, fal{}, nk - 3);
  ktile(std::integral_constant<int, 0>{}, fal{}, nk - 2);
  ktile(std::integral_constant<int, -1>{}, fal{}, nk - 1);

#pragma unroll
  for (int m = 0; m < 8; ++m)
#pragma unroll
    for (int n = 0; n < 4; ++n) {
      const int col = n0 + wc * 64 + n * 16 + l15;
      const float bv = bias[col];
#pragma unroll
      for (int r = 0; r < 4; ++r) {
        const int row = m0 + wr * 128 + m * 16 + lg * 4 + r;
        if constexpr (OBF)
          ((ushort*)Cv)[(size_t)row * N + col] = f2bf(acc[m][n][r] + bv);
        else
          ((float*)Cv)[(size_t)row * N + col] = acc[m][n][r] + bv;
      }
    }
}

// ---------------- causal depthwise conv(K=4) + bias + RoPE, vectorized x4 ----------------
__global__ __launch_bounds__(256) void conv_rope(
    const ushort* __restrict__ qkv, const float* __restrict__ cwT,
    const float* __restrict__ cb, const float* __restrict__ cosT,
    const float* __restrict__ sinT, ushort* __restrict__ Qo,
    ushort* __restrict__ Ko, ushort* __restrict__ Vo) {
  const int token = blockIdx.x;            // b*S + s
  const int s = token & (S_LEN - 1);
  const int p = blockIdx.y * 256 + threadIdx.x;   // 0..511

  auto conv4 = [&](int c0, float out[4]) {
    const float4 bb = *(const float4*)&cb[c0];
    out[0] = bb.x; out[1] = bb.y; out[2] = bb.z; out[3] = bb.w;
#pragma unroll
    for (int j = 0; j < 4; j++) {
      int ss = s - 3 + j;
      if (ss >= 0) {
        ushort4 v = *(const ushort4*)&qkv[(size_t)(token - 3 + j) * QKVD + c0];
        const float4 w = *(const float4*)&cwT[j * QKVD + c0];
        out[0] += bf2f(v.x) * w.x;
        out[1] += bf2f(v.y) * w.y;
        out[2] += bf2f(v.z) * w.z;
        out[3] += bf2f(v.w) * w.w;
      }
    }
  };

  if (p < 256) {                  // Q: h = p>>4, d0 = (p&15)*4; pre-scaled
    const int h = p >> 4, d0 = (p & 15) * 4;
    const int c1 = h * 128 + d0;
    float x1[4], x2[4];
    conv4(c1, x1); conv4(c1 + 64, x2);
    const float4 co = *(const float4*)&cosT[s * 64 + d0];
    const float4 si = *(const float4*)&sinT[s * 64 + d0];
    ushort4 o1, o2v;
    o1.x = f2bf((x1[0] * co.x - x2[0] * si.x) * QSCALE);
    o1.y = f2bf((x1[1] * co.y - x2[1] * si.y) * QSCALE);
    o1.z = f2bf((x1[2] * co.z - x2[2] * si.z) * QSCALE);
    o1.w = f2bf((x1[3] * co.w - x2[3] * si.w) * QSCALE);
    o2v.x = f2bf((x2[0] * co.x + x1[0] * si.x) * QSCALE);
    o2v.y = f2bf((x2[1] * co.y + x1[1] * si.y) * QSCALE);
    o2v.z = f2bf((x2[2] * co.z + x1[2] * si.z) * QSCALE);
    o2v.w = f2bf((x2[3] * co.w + x1[3] * si.w) * QSCALE);
    const size_t base = ((size_t)token * NH + h) * HDIM + d0;
    *(ushort4*)&Qo[base] = o1;
    *(ushort4*)&Qo[base + 64] = o2v;
  } else if (p < 320) {           // K: idx = p-256: h = idx>>4, d0 = (idx&15)*4
    const int idx = p - 256, h = idx >> 4, d0 = (idx & 15) * 4;
    const int c1 = 2048 + h * 128 + d0;
    float x1[4], x2[4];
    conv4(c1, x1); conv4(c1 + 64, x2);
    const float4 co = *(const float4*)&cosT[s * 64 + d0];
    const float4 si = *(const float4*)&sinT[s * 64 + d0];
    ushort4 o1, o2v;
    o1.x = f2bf(x1[0] * co.x - x2[0] * si.x);
    o1.y = f2bf(x1[1] * co.y - x2[1] * si.y);
    o1.z = f2bf(x1[2] * co.z - x2[2] * si.z);
    o1.w = f2bf(x1[3] * co.w - x2[3] * si.w);
    o2v.x = f2bf(x2[0] * co.x + x1[0] * si.x);
    o2v.y = f2bf(x2[1] * co.y + x1[1] * si.y);
    o2v.z = f2bf(x2[2] * co.z + x1[2] * si.z);
    o2v.w = f2bf(x2[3] * co.w + x1[3] * si.w);
    const size_t base = ((size_t)token * NKV + h) * HDIM + d0;
    *(ushort4*)&Ko[base] = o1;
    *(ushort4*)&Ko[base + 64] = o2v;
  } else if (p < 448) {           // V: idx = p-320 in [0,128): c0 = 2560 + idx*4
    const int idx = p - 320;
    const int c0 = 2560 + idx * 4;
    float v[4];
    conv4(c0, v);
    const int hd = idx * 4;
    const int h = hd >> 7, d = hd & 127;
    ushort4 o;
    o.x = f2bf(v[0]); o.y = f2bf(v[1]); o.z = f2bf(v[2]); o.w = f2bf(v[3]);
    *(ushort4*)&Vo[((size_t)token * NKV + h) * HDIM + d] = o;
  }
}

// ---------------- V transpose: Vb[b*S+s][kvh][d] -> Vt[(b*NKV+kvh)*128 + d][s] ----------------
__global__ __launch_bounds__(256) void transpose_v(const ushort* __restrict__ Vb,
                                                   ushort* __restrict__ Vt) {
  __shared__ ushort t[64][65];
  const int tid = threadIdx.x;
  const int s0 = blockIdx.x * 64, d0 = blockIdx.y * 64;
  const int g = blockIdx.z;                       // b*NKV + kvh
  const int b = g >> 2, kvh = g & 3;
#pragma unroll
  for (int p = 0; p < 8; p++) {
    int idx = p * 256 + tid;                      // [0,2048)
    int r = idx >> 5, c2 = (idx & 31) * 2;
    ushort2 v = *(const ushort2*)&Vb[((size_t)(b * S_LEN + s0 + r) * NKV + kvh) * HDIM + d0 + c2];
    t[r][c2] = v.x; t[r][c2 + 1] = v.y;
  }
  __syncthreads();
#pragma unroll
  for (int p = 0; p < 8; p++) {
    int idx = p * 256 + tid;
    int dr = idx >> 5, sc2 = (idx & 31) * 2;
    ushort2 v; v.x = t[sc2][dr]; v.y = t[sc2 + 1][dr];
    *(ushort2*)&Vt[((size_t)g * HDIM + d0 + dr) * S_LEN + s0 + sc2] = v;
  }
}

// ---------------- causal GQA flash attention: 8-wave blocks (4 heads x 2 q-groups) ----------------
// grid (B*NKV, 64), 512 thr. All 8 waves share one 48KB K-dbuf + single-V
// staging (per-wave staging instrs halve); wave wid handles head kvh*4+(wid&3),
// q-rows qb*32+(wid>>2)*16. Both q-groups need the same tile count (32-row
// groups never straddle an extra 64-tile), so the staged loop is uniform.
// 2 blocks/CU (96KB LDS) = 16 waves/CU vs 12 before. Per-wave body = r23.
__global__ __launch_bounds__(512, 2) void attn(
    const ushort* __restrict__ Q, const ushort* __restrict__ K,
    const ushort* __restrict__ Vt, ushort* __restrict__ ctx) {
  __shared__ __align__(16) ushort Ks[2][64 * 128];   // [key][d], chunk(16) ^= row&7
  __shared__ __align__(16) ushort Vs[128 * 64];      // [d][key], chunk(8)  ^= d&7
  const int tid = threadIdx.x;
  const int wid = tid >> 6, lane = tid & 63;
  const int l15 = lane & 15, lg = lane >> 4;
  const int bkv = blockIdx.x;                   // b*NKV + kvh; maps 1:1 to an XCD
  const int b = bkv >> 2, kvh = bkv & 3;
  const int h = kvh * 4 + (wid & 3);            // 4 heads of the group
  const int qb = (gridDim.y - 1) - blockIdx.y;  // longest blocks dispatch first
  const int q0 = qb * 32 + (wid >> 2) * 16;     // 2 q-groups of 16 rows

  const ushort* Kbase  = K  + ((size_t)b * S_LEN * NKV + kvh) * HDIM;
  const ushort* Vtbase = Vt + (size_t)bkv * HDIM * S_LEN;

  short8 qf[4];
#pragma unroll
  for (int kd = 0; kd < 4; kd++)
    qf[kd] = *(const short8*)&Q[(((size_t)(b * S_LEN + q0 + l15)) * NH + h) * HDIM + kd * 32 + lg * 8];

  auto stageK = [&](int tile, int bufi) {
    const int j0t = tile * 64;
#pragma unroll
    for (int p = 0; p < 2; ++p) {
      const int i = wid * 2 + p;                // 0..15 across 8 waves
      const int row = i * 4 + (lane >> 4);      // key row 0..63
      const int cs  = (lane & 15) ^ (row & 7);
      load_lds16(Kbase + (size_t)(j0t + row) * (NKV * HDIM) + cs * 8,
                 &Ks[bufi][i * 512]);
    }
  };
  auto stageV = [&](int tile) {
    const int j0t = tile * 64;
#pragma unroll
    for (int p = 0; p < 2; ++p) {
      const int i = wid * 2 + p;                // 0..15 across 8 waves
      const int d  = i * 8 + (lane >> 3);       // d row 0..127
      const int cs = (lane & 7) ^ (d & 7);
      load_lds16(Vtbase + (size_t)d * S_LEN + j0t + cs * 8,
                 &Vs[i * 512]);
    }
  };

  f32x4 o2[8] = {};
  float m_run = -3e30f, l_run = 0.f;
  const int ntile = (qb * 32 + 31) / 64 + 1;    // uniform across both q-groups
  const int qrow = q0 + l15;

  stageK(0, 0);
  __syncthreads();
  int buf = 0;
  for (int jt = 0; jt < ntile; ++jt) {
    const int j0 = jt * 64;
    if (jt + 1 < ntile) stageK(jt + 1, buf ^ 1);
    stageV(jt);                                  // lands under QK^T+softmax

    f32x4 sa[4] = {};
#pragma unroll
    for (int t = 0; t < 4; ++t) {
      const int r = t * 16 + l15;
#pragma unroll
      for (int kd = 0; kd < 4; ++kd) {
        short8 kf = *(const short8*)&Ks[buf][r * 128 + (((kd * 4 + lg) ^ (r & 7)) * 8)];
        sa[t] = __builtin_amdgcn_mfma_f32_16x16x32_bf16(kf, qf[kd], sa[t], 0, 0, 0);
      }
    }

    float pv[4][4];
    float mx = -3e30f;
#pragma unroll
    for (int t = 0; t < 4; ++t)
#pragma unroll
      for (int r = 0; r < 4; ++r) {
        float v = sa[t][r];
        if (j0 + t * 16 + lg * 4 + r > qrow) v = -3e30f;   // causal mask
        pv[t][r] = v;
        mx = fmaxf(mx, v);
      }
    mx = fmaxf(mx, __shfl_xor(mx, 16));
    mx = fmaxf(mx, __shfl_xor(mx, 32));
    // T13 defer-rescale: skip the O-wide rescale while max growth <= 8.
    if (!__all(mx <= m_run + 8.f)) {
      const float mnew = fmaxf(m_run, mx);
      const float fac = fexp2(m_run - mnew);
      m_run = mnew;
      l_run *= fac;
#pragma unroll
      for (int dt = 0; dt < 8; ++dt)
#pragma unroll
        for (int r = 0; r < 4; ++r) o2[dt][r] *= fac;
    }
    float sum = 0.f;
#pragma unroll
    for (int t = 0; t < 4; ++t)
#pragma unroll
      for (int r = 0; r < 4; ++r) {
        float p = fexp2(pv[t][r] - m_run);       // <= 2^8
        pv[t][r] = p;
        sum += p;
      }
    sum += __shfl_xor(sum, 16);
    sum += __shfl_xor(sum, 32);
    l_run += sum;

    unsigned pk[4][2];
#pragma unroll
    for (int t = 0; t < 4; ++t)
#pragma unroll
      for (int p = 0; p < 2; ++p)
        pk[t][p] = cvt_pk_bf16(pv[t][2 * p], pv[t][2 * p + 1]);

    union U8 { unsigned u[4]; short8 s; } pfk[2];
#pragma unroll
    for (int ks = 0; ks < 2; ++ks)
#pragma unroll
      for (int j = 0; j < 4; ++j) {
        const int src = ((lg & 1) * 2 + (j >> 1)) * 16 + l15;
        unsigned v0 = __shfl((int)pk[ks * 2][j & 1], src);
        unsigned v1 = __shfl((int)pk[ks * 2 + 1][j & 1], src);
        pfk[ks].u[j] = (lg >= 2) ? v1 : v0;
      }

    __syncthreads();   // V(jt) writes visible to all waves before PV reads

#pragma unroll
    for (int dt = 0; dt < 8; ++dt) {
      const int d = dt * 16 + l15;
#pragma unroll
      for (int ks = 0; ks < 2; ++ks) {
        short8 vf = *(const short8*)&Vs[d * 64 + (((ks * 4 + lg) ^ (d & 7)) * 8)];
        o2[dt] = __builtin_amdgcn_mfma_f32_16x16x32_bf16(vf, pfk[ks].s, o2[dt], 0, 0, 0);
      }
    }

    __syncthreads();   // V reads done before next stageV; Ks[buf^1] landed
    buf ^= 1;
  }

  const float inv_l = 1.f / l_run;
  const size_t obase = (((size_t)(b * S_LEN + q0 + l15)) * NH + h) * HDIM;
#pragma unroll
  for (int dt = 0; dt < 8; ++dt) {
    ushort4 w;
    w.x = f2bf(o2[dt][0] * inv_l);
    w.y = f2bf(o2[dt][1] * inv_l);
    w.z = f2bf(o2[dt][2] * inv_l);
    w.w = f2bf(o2[dt][3] * inv_l);
    *(ushort4*)&ctx[obase + dt * 16 + lg * 4] = w;
  }
}

// ---------------- launcher ----------------
extern "C" void kernel_launch(void* const* d_in, const int* in_sizes, int n_in,
                              void* d_out, int out_size, void* d_ws, size_t ws_size,
                              hipStream_t stream) {
  const float* x      = (const float*)d_in[0];
  const float* w_in   = (const float*)d_in[1];
  const float* b_in   = (const float*)d_in[2];
  const float* conv_w = (const float*)d_in[3];
  const float* conv_b = (const float*)d_in[4];
  const float* w_out  = (const float*)d_in[5];
  const float* b_out  = (const float*)d_in[6];
  float* out = (float*)d_out;

  char* ws = (char*)d_ws;
  size_t off = 0;
  ushort* xbf  = (ushort*)(ws + off); off += (size_t)4096 * 2048 * 2;  // x bf16; later reused as ctx
  ushort* wibf = (ushort*)(ws + off); off += (size_t)3072 * 2048 * 2;
  ushort* wobf = (ushort*)(ws + off); off += (size_t)2048 * 2048 * 2;
  ushort* qkv  = (ushort*)(ws + off); off += (size_t)4096 * 3072 * 2;  // bf16; dead after conv_rope
  ushort* Qb   = (ushort*)(ws + off); off += (size_t)4096 * 16 * 128 * 2;
  ushort* Kb   = (ushort*)(ws + off); off += (size_t)4096 * 4 * 128 * 2;
  ushort* Vb   = (ushort*)(ws + off); off += (size_t)4096 * 4 * 128 * 2;
  float*  cosT = (float*)(ws + off);  off += (size_t)2048 * 64 * 4;
  float*  sinT = (float*)(ws + off);  off += (size_t)2048 * 64 * 4;
  float*  cwT  = (float*)(ws + off);  off += (size_t)4 * QKVD * 4;     // transposed conv weights
  ushort* Vtb  = (ushort*)qkv;        // alias: transposed V lives in dead qkv buffer (8 MB)

  cast3<<<18432, 256, 0, stream>>>(x, w_in, w_out, xbf, wibf, wobf);
  transpose_cw<<<48, 256, 0, stream>>>(conv_w, cwT);
  rope_table<<<512, 256, 0, stream>>>(cosT, sinT);

  gemm256<true><<<192, 512, 0, stream>>>(xbf, wibf, b_in, qkv, 4096, 3072, 2048);
  conv_rope<<<dim3(4096, 2), 256, 0, stream>>>(qkv, cwT, conv_b, cosT, sinT, Qb, Kb, Vb);
  transpose_v<<<dim3(32, 2, 8), 256, 0, stream>>>(Vb, Vtb);
  attn<<<dim3(8, 64), 512, 0, stream>>>(Qb, Kb, Vtb, xbf);
  gemm128<false><<<512, 256, 0, stream>>>(xbf, wobf, b_out, out, 4096, 2048, 2048);
}

// Round 25
// 209.787 us; speedup vs baseline: 1.0339x; 1.0339x over previous
//
#include <hip/hip_runtime.h>
#include <type_traits>

#define S_LEN 2048
#define BATCH 2
#define EDIM  2048
#define NH    16
#define NKV   4
#define HDIM  128
#define QKVD  3072
// ATT_SCALE * log2(e): folded into Q at conv_rope time -> scores in log2 domain
#define QSCALE 0.12751579107188777f

typedef __attribute__((ext_vector_type(8))) short short8;
typedef __attribute__((ext_vector_type(4))) float f32x4;

__device__ __forceinline__ ushort f2bf(float f) {
  union { float f; unsigned u; } un; un.f = f;
  unsigned u = un.u + 0x7fffu + ((un.u >> 16) & 1u);
  return (ushort)(u >> 16);
}
__device__ __forceinline__ float bf2f(ushort h) {
  union { unsigned u; float f; } un; un.u = ((unsigned)h) << 16;
  return un.f;
}
__device__ __forceinline__ unsigned cvt_pk_bf16(float lo, float hi) {
  unsigned r;
  asm("v_cvt_pk_bf16_f32 %0, %1, %2" : "=v"(r) : "v"(lo), "v"(hi));
  return r;
}
__device__ __forceinline__ float fexp2(float x) { return __builtin_amdgcn_exp2f(x); }

__device__ __forceinline__ void load_lds16(const void* g, void* l) {
  __builtin_amdgcn_global_load_lds((const __attribute__((address_space(1))) void*)g,
                                   (__attribute__((address_space(3))) void*)l,
                                   16, 0, 0);
}

// ---------------- fused f32 -> bf16 casts (x, w_in, w_out) ----------------
__global__ __launch_bounds__(256) void cast3(const float* __restrict__ a,
                                             const float* __restrict__ b,
                                             const float* __restrict__ c,
                                             ushort* __restrict__ oa,
                                             ushort* __restrict__ ob,
                                             ushort* __restrict__ oc) {
  int i = blockIdx.x * 256 + threadIdx.x;       // [0, 4718592)
  const float* s; ushort* d; int j;
  if (i < 2097152)      { s = a; d = oa; j = i; }
  else if (i < 3670016) { s = b; d = ob; j = i - 2097152; }
  else                  { s = c; d = oc; j = i - 3670016; }
  float4 v = ((const float4*)s)[j];
  ushort4 o;
  o.x = f2bf(v.x); o.y = f2bf(v.y); o.z = f2bf(v.z); o.w = f2bf(v.w);
  ((ushort4*)d)[j] = o;
}

// ---------------- conv weight transpose: cw[c][j] -> cwT[j][c] (4 x 3072 f32) ----------------
__global__ __launch_bounds__(256) void transpose_cw(const float* __restrict__ cw,
                                                    float* __restrict__ cwT) {
  int i = blockIdx.x * 256 + threadIdx.x;       // [0, 12288)
  int c = i >> 2, j = i & 3;
  cwT[j * QKVD + c] = cw[i];
}

// ---------------- RoPE cos/sin table: [S][64] ----------------
__global__ __launch_bounds__(256) void rope_table(float* __restrict__ cosT,
                                                  float* __restrict__ sinT) {
  int i = blockIdx.x * 256 + threadIdx.x;   // S*64 total
  int s = i >> 6, d = i & 63;
  float inv = expf(-(float)d * 0.14391156831212787f);   // 10000^(-d/64)
  float f = (float)s * inv;
  float sv, cv;
  sincosf(f, &sv, &cv);
  cosT[i] = cv;
  sinT[i] = sv;
}

// ---------------- 128x128 ring-4 bf16 NT GEMM (r22-proven) ----------------
template <bool OBF>
__global__ __launch_bounds__(256, 2) void gemm128(
    const ushort* __restrict__ A, const ushort* __restrict__ Bt,
    const float* __restrict__ bias, void* __restrict__ Cv,
    int M, int N, int K) {
  __shared__ __align__(16) ushort LA[4][4096];   // [slot][128 rows x 32 cols]
  __shared__ __align__(16) ushort LB[4][4096];
  const int tid = threadIdx.x;
  const int wid = tid >> 6, lane = tid & 63;
  const int l15 = lane & 15, lg = lane >> 4;
  const int wr = wid >> 1, wc = wid & 1;
  const int nTn = N >> 7;
  const int cpx = gridDim.x >> 3;                 // grid divisible by 8
  const int swz = ((int)blockIdx.x & 7) * cpx + ((int)blockIdx.x >> 3);
  const int m0 = (swz / nTn) * 128, n0 = (swz % nTn) * 128;
  const ushort* Ag = A + (size_t)m0 * K;
  const ushort* Bg = Bt + (size_t)n0 * K;
  const int coff = (lg ^ ((l15 >> 1) & 3)) * 8;
  const int abase = (wr * 64 + l15) * 32 + coff;
  const int bbase = (wc * 64 + l15) * 32 + coff;
  const int nk = K >> 5;

  f32x4 acc[4][4] = {};

  auto stage_one = [&](const ushort* G, ushort* Ls, int k0) {
#pragma unroll
    for (int i = 0; i < 2; ++i) {
      const int c = i * 256 + tid;                // chunk 0..511 (16B each)
      const int row = c >> 2, cc = c & 3;
      const int scc = cc ^ ((row >> 1) & 3);      // inverse-swizzle the SOURCE
      load_lds16(G + (size_t)row * K + k0 + scc * 8,
                 Ls + (i * 256 + wid * 64) * 8);
    }
  };

#pragma unroll
  for (int t = 0; t < 3; ++t) {
    stage_one(Ag, LA[t], t * 32);
    stage_one(Bg, LB[t], t * 32);
  }
  asm volatile("s_waitcnt vmcnt(8)" ::: "memory");
  __builtin_amdgcn_s_barrier();

  auto ktile = [&](auto VMC, auto STG, int t) {
    constexpr int VM = decltype(VMC)::value;
    constexpr bool STAGE = decltype(STG)::value;
    const int slot = t & 3;
    const ushort* Las = LA[slot];
    const ushort* Lbs = LB[slot];
    short8 afr[4], bfr[4];
#pragma unroll
    for (int n = 0; n < 4; ++n) bfr[n] = *(const short8*)&Lbs[bbase + n * 512];
#pragma unroll
    for (int m = 0; m < 4; ++m) afr[m] = *(const short8*)&Las[abase + m * 512];
    if constexpr (STAGE) {
      stage_one(Ag, LA[(t + 3) & 3], (t + 3) * 32);
      stage_one(Bg, LB[(t + 3) & 3], (t + 3) * 32);
    }
    __builtin_amdgcn_s_setprio(1);
#pragma unroll
    for (int m = 0; m < 4; ++m)
#pragma unroll
      for (int n = 0; n < 4; ++n)
        acc[m][n] = __builtin_amdgcn_mfma_f32_16x16x32_bf16(afr[m], bfr[n], acc[m][n], 0, 0, 0);
    __builtin_amdgcn_s_setprio(0);
    if constexpr (VM == 8)      asm volatile("s_waitcnt vmcnt(8)" ::: "memory");
    else if constexpr (VM == 4) asm volatile("s_waitcnt vmcnt(4)" ::: "memory");
    else if constexpr (VM == 0) asm volatile("s_waitcnt vmcnt(0)" ::: "memory");
    __builtin_amdgcn_s_barrier();
  };

  using tru = std::integral_constant<bool, true>;
  using fal = std::integral_constant<bool, false>;
  for (int t = 0; t + 3 < nk; ++t)
    ktile(std::integral_constant<int, 8>{}, tru{}, t);
  ktile(std::integral_constant<int, 4>{}, fal{}, nk - 3);
  ktile(std::integral_constant<int, 0>{}, fal{}, nk - 2);
  ktile(std::integral_constant<int, -1>{}, fal{}, nk - 1);

#pragma unroll
  for (int m = 0; m < 4; ++m)
#pragma unroll
    for (int n = 0; n < 4; ++n) {
      const int col = n0 + wc * 64 + n * 16 + l15;
      const float bv = bias[col];
#pragma unroll
      for (int r = 0; r < 4; ++r) {
        const int row = m0 + wr * 64 + m * 16 + lg * 4 + r;
        if constexpr (OBF)
          ((ushort*)Cv)[(size_t)row * N + col] = f2bf(acc[m][n][r] + bv);
        else
          ((float*)Cv)[(size_t)row * N + col] = acc[m][n][r] + bv;
      }
    }
}

// ---------------- 256x256 ring-4 bf16 NT GEMM, ONE barrier per K-tile (r17-proven) ----------------
template <bool OBF>
__global__ __launch_bounds__(512, 2) void gemm256(
    const ushort* __restrict__ A, const ushort* __restrict__ Bt,
    const float* __restrict__ bias, void* __restrict__ Cv,
    int M, int N, int K) {
  __shared__ __align__(16) ushort LA[4][8192];   // [slot][256 rows x 32 cols]
  __shared__ __align__(16) ushort LB[4][8192];
  const int tid = threadIdx.x;
  const int wid = tid >> 6, lane = tid & 63;
  const int l15 = lane & 15, lg = lane >> 4;
  const int wr = wid >> 2, wc = wid & 3;
  const int nTn = N >> 8;
  const int cpx = gridDim.x >> 3;                 // grid divisible by 8
  const int swz = ((int)blockIdx.x & 7) * cpx + ((int)blockIdx.x >> 3);
  const int m0 = (swz / nTn) * 256, n0 = (swz % nTn) * 256;
  const ushort* Ag = A + (size_t)m0 * K;
  const ushort* Bg = Bt + (size_t)n0 * K;
  const int coff = (lg ^ ((l15 >> 1) & 3)) * 8;
  const int abase = (wr * 128 + l15) * 32 + coff;
  const int bbase = (wc * 64 + l15) * 32 + coff;
  const int nk = K >> 5;

  f32x4 acc[8][4] = {};

  auto stage_one = [&](const ushort* G, ushort* Ls, int k0) {
#pragma unroll
    for (int i = 0; i < 2; ++i) {
      const int c = i * 512 + tid;                // chunk 0..1023
      const int row = c >> 2, cc = c & 3;
      const int scc = cc ^ ((row >> 1) & 3);      // inverse-swizzle the SOURCE
      load_lds16(G + (size_t)row * K + k0 + scc * 8,
                 Ls + (i * 512 + wid * 64) * 8);
    }
  };

#pragma unroll
  for (int t = 0; t < 3; ++t) {
    stage_one(Ag, LA[t], t * 32);
    stage_one(Bg, LB[t], t * 32);
  }
  asm volatile("s_waitcnt vmcnt(8)" ::: "memory");
  __builtin_amdgcn_s_barrier();

  auto ktile = [&](auto VMC, auto STG, int t) {
    constexpr int VM = decltype(VMC)::value;
    constexpr bool STAGE = decltype(STG)::value;
    const int slot = t & 3;
    const ushort* Las = LA[slot];
    const ushort* Lbs = LB[slot];
    short8 afr[8], bfr[4];
#pragma unroll
    for (int n = 0; n < 4; ++n) bfr[n] = *(const short8*)&Lbs[bbase + n * 512];
#pragma unroll
    for (int m = 0; m < 8; ++m) afr[m] = *(const short8*)&Las[abase + m * 512];
    if constexpr (STAGE) {
      stage_one(Ag, LA[(t + 3) & 3], (t + 3) * 32);
      stage_one(Bg, LB[(t + 3) & 3], (t + 3) * 32);
    }
    __builtin_amdgcn_s_setprio(1);
#pragma unroll
    for (int m = 0; m < 8; ++m)
#pragma unroll
      for (int n = 0; n < 4; ++n)
        acc[m][n] = __builtin_amdgcn_mfma_f32_16x16x32_bf16(afr[m], bfr[n], acc[m][n], 0, 0, 0);
    __builtin_amdgcn_s_setprio(0);
    if constexpr (VM == 8)      asm volatile("s_waitcnt vmcnt(8)" ::: "memory");
    else if constexpr (VM == 4) asm volatile("s_waitcnt vmcnt(4)" ::: "memory");
    else if constexpr (VM == 0) asm volatile("s_waitcnt vmcnt(0)" ::: "memory");
    __builtin_amdgcn_s_barrier();
  };

  using tru = std::integral_constant<bool, true>;
  using fal = std::integral_constant<bool, false>;
  for (int t = 0; t + 3 < nk; ++t)
    ktile(std::integral_constant<int, 8>{}, tru{}, t);
  ktile(std::integral_constant<int, 4>{}, fal{}, nk - 3);
  ktile(std::integral_constant<int, 0>{}, fal{}, nk - 2);
  ktile(std::integral_constant<int, -1>{}, fal{}, nk - 1);

#pragma unroll
  for (int m = 0; m < 8; ++m)
#pragma unroll
    for (int n = 0; n < 4; ++n) {
      const int col = n0 + wc * 64 + n * 16 + l15;
      const float bv = bias[col];
#pragma unroll
      for (int r = 0; r < 4; ++r) {
        const int row = m0 + wr * 128 + m * 16 + lg * 4 + r;
        if constexpr (OBF)
          ((ushort*)Cv)[(size_t)row * N + col] = f2bf(acc[m][n][r] + bv);
        else
          ((float*)Cv)[(size_t)row * N + col] = acc[m][n][r] + bv;
      }
    }
}

// ---------------- causal depthwise conv(K=4) + bias + RoPE, vectorized x4 ----------------
__global__ __launch_bounds__(256) void conv_rope(
    const ushort* __restrict__ qkv, const float* __restrict__ cwT,
    const float* __restrict__ cb, const float* __restrict__ cosT,
    const float* __restrict__ sinT, ushort* __restrict__ Qo,
    ushort* __restrict__ Ko, ushort* __restrict__ Vo) {
  const int token = blockIdx.x;            // b*S + s
  const int s = token & (S_LEN - 1);
  const int p = blockIdx.y * 256 + threadIdx.x;   // 0..511

  auto conv4 = [&](int c0, float out[4]) {
    const float4 bb = *(const float4*)&cb[c0];
    out[0] = bb.x; out[1] = bb.y; out[2] = bb.z; out[3] = bb.w;
#pragma unroll
    for (int j = 0; j < 4; j++) {
      int ss = s - 3 + j;
      if (ss >= 0) {
        ushort4 v = *(const ushort4*)&qkv[(size_t)(token - 3 + j) * QKVD + c0];
        const float4 w = *(const float4*)&cwT[j * QKVD + c0];
        out[0] += bf2f(v.x) * w.x;
        out[1] += bf2f(v.y) * w.y;
        out[2] += bf2f(v.z) * w.z;
        out[3] += bf2f(v.w) * w.w;
      }
    }
  };

  if (p < 256) {                  // Q: h = p>>4, d0 = (p&15)*4; pre-scaled
    const int h = p >> 4, d0 = (p & 15) * 4;
    const int c1 = h * 128 + d0;
    float x1[4], x2[4];
    conv4(c1, x1); conv4(c1 + 64, x2);
    const float4 co = *(const float4*)&cosT[s * 64 + d0];
    const float4 si = *(const float4*)&sinT[s * 64 + d0];
    ushort4 o1, o2v;
    o1.x = f2bf((x1[0] * co.x - x2[0] * si.x) * QSCALE);
    o1.y = f2bf((x1[1] * co.y - x2[1] * si.y) * QSCALE);
    o1.z = f2bf((x1[2] * co.z - x2[2] * si.z) * QSCALE);
    o1.w = f2bf((x1[3] * co.w - x2[3] * si.w) * QSCALE);
    o2v.x = f2bf((x2[0] * co.x + x1[0] * si.x) * QSCALE);
    o2v.y = f2bf((x2[1] * co.y + x1[1] * si.y) * QSCALE);
    o2v.z = f2bf((x2[2] * co.z + x1[2] * si.z) * QSCALE);
    o2v.w = f2bf((x2[3] * co.w + x1[3] * si.w) * QSCALE);
    const size_t base = ((size_t)token * NH + h) * HDIM + d0;
    *(ushort4*)&Qo[base] = o1;
    *(ushort4*)&Qo[base + 64] = o2v;
  } else if (p < 320) {           // K: idx = p-256: h = idx>>4, d0 = (idx&15)*4
    const int idx = p - 256, h = idx >> 4, d0 = (idx & 15) * 4;
    const int c1 = 2048 + h * 128 + d0;
    float x1[4], x2[4];
    conv4(c1, x1); conv4(c1 + 64, x2);
    const float4 co = *(const float4*)&cosT[s * 64 + d0];
    const float4 si = *(const float4*)&sinT[s * 64 + d0];
    ushort4 o1, o2v;
    o1.x = f2bf(x1[0] * co.x - x2[0] * si.x);
    o1.y = f2bf(x1[1] * co.y - x2[1] * si.y);
    o1.z = f2bf(x1[2] * co.z - x2[2] * si.z);
    o1.w = f2bf(x1[3] * co.w - x2[3] * si.w);
    o2v.x = f2bf(x2[0] * co.x + x1[0] * si.x);
    o2v.y = f2bf(x2[1] * co.y + x1[1] * si.y);
    o2v.z = f2bf(x2[2] * co.z + x1[2] * si.z);
    o2v.w = f2bf(x2[3] * co.w + x1[3] * si.w);
    const size_t base = ((size_t)token * NKV + h) * HDIM + d0;
    *(ushort4*)&Ko[base] = o1;
    *(ushort4*)&Ko[base + 64] = o2v;
  } else if (p < 448) {           // V: idx = p-320 in [0,128): c0 = 2560 + idx*4
    const int idx = p - 320;
    const int c0 = 2560 + idx * 4;
    float v[4];
    conv4(c0, v);
    const int hd = idx * 4;
    const int h = hd >> 7, d = hd & 127;
    ushort4 o;
    o.x = f2bf(v[0]); o.y = f2bf(v[1]); o.z = f2bf(v[2]); o.w = f2bf(v[3]);
    *(ushort4*)&Vo[((size_t)token * NKV + h) * HDIM + d] = o;
  }
}

// ---------------- V transpose: Vb[b*S+s][kvh][d] -> Vt[(b*NKV+kvh)*128 + d][s] ----------------
__global__ __launch_bounds__(256) void transpose_v(const ushort* __restrict__ Vb,
                                                   ushort* __restrict__ Vt) {
  __shared__ ushort t[64][65];
  const int tid = threadIdx.x;
  const int s0 = blockIdx.x * 64, d0 = blockIdx.y * 64;
  const int g = blockIdx.z;                       // b*NKV + kvh
  const int b = g >> 2, kvh = g & 3;
#pragma unroll
  for (int p = 0; p < 8; p++) {
    int idx = p * 256 + tid;                      // [0,2048)
    int r = idx >> 5, c2 = (idx & 31) * 2;
    ushort2 v = *(const ushort2*)&Vb[((size_t)(b * S_LEN + s0 + r) * NKV + kvh) * HDIM + d0 + c2];
    t[r][c2] = v.x; t[r][c2 + 1] = v.y;
  }
  __syncthreads();
#pragma unroll
  for (int p = 0; p < 8; p++) {
    int idx = p * 256 + tid;
    int dr = idx >> 5, sc2 = (idx & 31) * 2;
    ushort2 v; v.x = t[sc2][dr]; v.y = t[sc2 + 1][dr];
    *(ushort2*)&Vt[((size_t)g * HDIM + d0 + dr) * S_LEN + s0 + sc2] = v;
  }
}

// ---------------- causal GQA flash attention: K dbuf + single-V + defer-rescale (r23-proven) ----------------
__global__ __launch_bounds__(256, 3) void attn(
    const ushort* __restrict__ Q, const ushort* __restrict__ K,
    const ushort* __restrict__ Vt, ushort* __restrict__ ctx) {
  __shared__ __align__(16) ushort Ks[2][64 * 128];   // [key][d], chunk(16) ^= row&7
  __shared__ __align__(16) ushort Vs[128 * 64];      // [d][key], chunk(8)  ^= d&7
  const int tid = threadIdx.x;
  const int wid = tid >> 6, lane = tid & 63;
  const int l15 = lane & 15, lg = lane >> 4;
  const int bkv = blockIdx.x;                   // b*NKV + kvh; maps 1:1 to an XCD
  const int b = bkv >> 2, kvh = bkv & 3;
  const int h = kvh * 4 + wid;                  // wave = one q-head of the group
  const int qb = (gridDim.y - 1) - blockIdx.y;  // longest blocks dispatch first
  const int q0 = qb * 16;

  const ushort* Kbase  = K  + ((size_t)b * S_LEN * NKV + kvh) * HDIM;
  const ushort* Vtbase = Vt + (size_t)bkv * HDIM * S_LEN;

  short8 qf[4];
#pragma unroll
  for (int kd = 0; kd < 4; kd++)
    qf[kd] = *(const short8*)&Q[(((size_t)(b * S_LEN + q0 + l15)) * NH + h) * HDIM + kd * 32 + lg * 8];

  auto stageK = [&](int tile, int bufi) {
    const int j0t = tile * 64;
#pragma unroll
    for (int p = 0; p < 4; ++p) {
      const int i = wid * 4 + p;                // 0..15
      const int row = i * 4 + (lane >> 4);      // key row 0..63
      const int cs  = (lane & 15) ^ (row & 7);
      load_lds16(Kbase + (size_t)(j0t + row) * (NKV * HDIM) + cs * 8,
                 &Ks[bufi][i * 512]);
    }
  };
  auto stageV = [&](int tile) {
    const int j0t = tile * 64;
#pragma unroll
    for (int p = 0; p < 4; ++p) {
      const int i = wid * 4 + p;                // 0..15
      const int d  = i * 8 + (lane >> 3);       // d row 0..127
      const int cs = (lane & 7) ^ (d & 7);
      load_lds16(Vtbase + (size_t)d * S_LEN + j0t + cs * 8,
                 &Vs[i * 512]);
    }
  };

  f32x4 o2[8] = {};
  float m_run = -3e30f, l_run = 0.f;
  const int ntile = q0 / 64 + 1;
  const int qrow = q0 + l15;

  stageK(0, 0);
  __syncthreads();
  int buf = 0;
  for (int jt = 0; jt < ntile; ++jt) {
    const int j0 = jt * 64;
    if (jt + 1 < ntile) stageK(jt + 1, buf ^ 1);
    stageV(jt);                                  // lands under QK^T+softmax

    f32x4 sa[4] = {};
#pragma unroll
    for (int t = 0; t < 4; ++t) {
      const int r = t * 16 + l15;
#pragma unroll
      for (int kd = 0; kd < 4; ++kd) {
        short8 kf = *(const short8*)&Ks[buf][r * 128 + (((kd * 4 + lg) ^ (r & 7)) * 8)];
        sa[t] = __builtin_amdgcn_mfma_f32_16x16x32_bf16(kf, qf[kd], sa[t], 0, 0, 0);
      }
    }

    float pv[4][4];
    float mx = -3e30f;
#pragma unroll
    for (int t = 0; t < 4; ++t)
#pragma unroll
      for (int r = 0; r < 4; ++r) {
        float v = sa[t][r];
        if (j0 + t * 16 + lg * 4 + r > qrow) v = -3e30f;   // causal mask
        pv[t][r] = v;
        mx = fmaxf(mx, v);
      }
    mx = fmaxf(mx, __shfl_xor(mx, 16));
    mx = fmaxf(mx, __shfl_xor(mx, 32));
    // T13 defer-rescale: skip the O-wide rescale while max growth <= 8
    // (P bounded by 2^8; first tile always rescales since m_run = -3e30).
    if (!__all(mx <= m_run + 8.f)) {
      const float mnew = fmaxf(m_run, mx);
      const float fac = fexp2(m_run - mnew);
      m_run = mnew;
      l_run *= fac;
#pragma unroll
      for (int dt = 0; dt < 8; ++dt)
#pragma unroll
        for (int r = 0; r < 4; ++r) o2[dt][r] *= fac;
    }
    float sum = 0.f;
#pragma unroll
    for (int t = 0; t < 4; ++t)
#pragma unroll
      for (int r = 0; r < 4; ++r) {
        float p = fexp2(pv[t][r] - m_run);       // <= 2^8
        pv[t][r] = p;
        sum += p;
      }
    sum += __shfl_xor(sum, 16);
    sum += __shfl_xor(sum, 32);
    l_run += sum;

    unsigned pk[4][2];
#pragma unroll
    for (int t = 0; t < 4; ++t)
#pragma unroll
      for (int p = 0; p < 2; ++p)
        pk[t][p] = cvt_pk_bf16(pv[t][2 * p], pv[t][2 * p + 1]);

    union U8 { unsigned u[4]; short8 s; } pfk[2];
#pragma unroll
    for (int ks = 0; ks < 2; ++ks)
#pragma unroll
      for (int j = 0; j < 4; ++j) {
        const int src = ((lg & 1) * 2 + (j >> 1)) * 16 + l15;
        unsigned v0 = __shfl((int)pk[ks * 2][j & 1], src);
        unsigned v1 = __shfl((int)pk[ks * 2 + 1][j & 1], src);
        pfk[ks].u[j] = (lg >= 2) ? v1 : v0;
      }

    __syncthreads();   // V(jt) writes visible to all waves before PV reads

#pragma unroll
    for (int dt = 0; dt < 8; ++dt) {
      const int d = dt * 16 + l15;
#pragma unroll
      for (int ks = 0; ks < 2; ++ks) {
        short8 vf = *(const short8*)&Vs[d * 64 + (((ks * 4 + lg) ^ (d & 7)) * 8)];
        o2[dt] = __builtin_amdgcn_mfma_f32_16x16x32_bf16(vf, pfk[ks].s, o2[dt], 0, 0, 0);
      }
    }

    __syncthreads();   // V reads done before next stageV; Ks[buf^1] landed
    buf ^= 1;
  }

  const float inv_l = 1.f / l_run;
  const size_t obase = (((size_t)(b * S_LEN + q0 + l15)) * NH + h) * HDIM;
#pragma unroll
  for (int dt = 0; dt < 8; ++dt) {
    ushort4 w;
    w.x = f2bf(o2[dt][0] * inv_l);
    w.y = f2bf(o2[dt][1] * inv_l);
    w.z = f2bf(o2[dt][2] * inv_l);
    w.w = f2bf(o2[dt][3] * inv_l);
    *(ushort4*)&ctx[obase + dt * 16 + lg * 4] = w;
  }
}

// ---------------- launcher ----------------
extern "C" void kernel_launch(void* const* d_in, const int* in_sizes, int n_in,
                              void* d_out, int out_size, void* d_ws, size_t ws_size,
                              hipStream_t stream) {
  const float* x      = (const float*)d_in[0];
  const float* w_in   = (const float*)d_in[1];
  const float* b_in   = (const float*)d_in[2];
  const float* conv_w = (const float*)d_in[3];
  const float* conv_b = (const float*)d_in[4];
  const float* w_out  = (const float*)d_in[5];
  const float* b_out  = (const float*)d_in[6];
  float* out = (float*)d_out;

  char* ws = (char*)d_ws;
  size_t off = 0;
  ushort* xbf  = (ushort*)(ws + off); off += (size_t)4096 * 2048 * 2;  // x bf16; later reused as ctx
  ushort* wibf = (ushort*)(ws + off); off += (size_t)3072 * 2048 * 2;
  ushort* wobf = (ushort*)(ws + off); off += (size_t)2048 * 2048 * 2;
  ushort* qkv  = (ushort*)(ws + off); off += (size_t)4096 * 3072 * 2;  // bf16; dead after conv_rope
  ushort* Qb   = (ushort*)(ws + off); off += (size_t)4096 * 16 * 128 * 2;
  ushort* Kb   = (ushort*)(ws + off); off += (size_t)4096 * 4 * 128 * 2;
  ushort* Vb   = (ushort*)(ws + off); off += (size_t)4096 * 4 * 128 * 2;
  float*  cosT = (float*)(ws + off);  off += (size_t)2048 * 64 * 4;
  float*  sinT = (float*)(ws + off);  off += (size_t)2048 * 64 * 4;
  float*  cwT  = (float*)(ws + off);  off += (size_t)4 * QKVD * 4;     // transposed conv weights
  ushort* Vtb  = (ushort*)qkv;        // alias: transposed V lives in dead qkv buffer (8 MB)

  cast3<<<18432, 256, 0, stream>>>(x, w_in, w_out, xbf, wibf, wobf);
  transpose_cw<<<48, 256, 0, stream>>>(conv_w, cwT);
  rope_table<<<512, 256, 0, stream>>>(cosT, sinT);

  gemm256<true><<<192, 512, 0, stream>>>(xbf, wibf, b_in, qkv, 4096, 3072, 2048);
  conv_rope<<<dim3(4096, 2), 256, 0, stream>>>(qkv, cwT, conv_b, cosT, sinT, Qb, Kb, Vb);
  transpose_v<<<dim3(32, 2, 8), 256, 0, stream>>>(Vb, Vtb);
  attn<<<dim3(8, 128), 256, 0, stream>>>(Qb, Kb, Vtb, xbf);
  gemm128<false><<<512, 256, 0, stream>>>(xbf, wobf, b_out, out, 4096, 2048, 2048);
}

// Round 26
// 205.960 us; speedup vs baseline: 1.0531x; 1.0186x over previous
//
#include <hip/hip_runtime.h>
#include <type_traits>

#define S_LEN 2048
#define BATCH 2
#define EDIM  2048
#define NH    16
#define NKV   4
#define HDIM  128
#define QKVD  3072
// ATT_SCALE * log2(e): folded into Q at conv_rope time -> scores in log2 domain
#define QSCALE 0.12751579107188777f

typedef __attribute__((ext_vector_type(8))) short short8;
typedef __attribute__((ext_vector_type(4))) float f32x4;

__device__ __forceinline__ ushort f2bf(float f) {
  union { float f; unsigned u; } un; un.f = f;
  unsigned u = un.u + 0x7fffu + ((un.u >> 16) & 1u);
  return (ushort)(u >> 16);
}
__device__ __forceinline__ float bf2f(ushort h) {
  union { unsigned u; float f; } un; un.u = ((unsigned)h) << 16;
  return un.f;
}
__device__ __forceinline__ unsigned cvt_pk_bf16(float lo, float hi) {
  unsigned r;
  asm("v_cvt_pk_bf16_f32 %0, %1, %2" : "=v"(r) : "v"(lo), "v"(hi));
  return r;
}
__device__ __forceinline__ float fexp2(float x) { return __builtin_amdgcn_exp2f(x); }

__device__ __forceinline__ void load_lds16(const void* g, void* l) {
  __builtin_amdgcn_global_load_lds((const __attribute__((address_space(1))) void*)g,
                                   (__attribute__((address_space(3))) void*)l,
                                   16, 0, 0);
}

// ---------------- fused prep: f32->bf16 casts + RoPE table + conv-w transpose ----------------
// All section boundaries are multiples of 256 -> no intra-block divergence.
__global__ __launch_bounds__(256) void prep(const float* __restrict__ a,
                                            const float* __restrict__ b,
                                            const float* __restrict__ c,
                                            const float* __restrict__ cw,
                                            ushort* __restrict__ oa,
                                            ushort* __restrict__ ob,
                                            ushort* __restrict__ oc,
                                            float* __restrict__ cosT,
                                            float* __restrict__ sinT,
                                            float* __restrict__ cwT) {
  int i = blockIdx.x * 256 + threadIdx.x;
  if (i < 4718592) {                              // cast sections (float4 each)
    const float* s; ushort* d; int j;
    if (i < 2097152)      { s = a; d = oa; j = i; }
    else if (i < 3670016) { s = b; d = ob; j = i - 2097152; }
    else                  { s = c; d = oc; j = i - 3670016; }
    float4 v = ((const float4*)s)[j];
    ushort4 o;
    o.x = f2bf(v.x); o.y = f2bf(v.y); o.z = f2bf(v.z); o.w = f2bf(v.w);
    ((ushort4*)d)[j] = o;
  } else if (i < 4849664) {                       // RoPE table: S*64 entries
    int k = i - 4718592;
    int s = k >> 6, d = k & 63;
    float inv = expf(-(float)d * 0.14391156831212787f);   // 10000^(-d/64)
    float f = (float)s * inv;
    float sv, cv;
    sincosf(f, &sv, &cv);
    cosT[k] = cv;
    sinT[k] = sv;
  } else {                                        // cw[c][j] -> cwT[j][c], 12288
    int k = i - 4849664;
    int cc = k >> 2, j = k & 3;
    cwT[j * QKVD + cc] = cw[k];
  }
}

// ---------------- 128x128 ring-4 bf16 NT GEMM (r22-proven) ----------------
template <bool OBF>
__global__ __launch_bounds__(256, 2) void gemm128(
    const ushort* __restrict__ A, const ushort* __restrict__ Bt,
    const float* __restrict__ bias, void* __restrict__ Cv,
    int M, int N, int K) {
  __shared__ __align__(16) ushort LA[4][4096];   // [slot][128 rows x 32 cols]
  __shared__ __align__(16) ushort LB[4][4096];
  const int tid = threadIdx.x;
  const int wid = tid >> 6, lane = tid & 63;
  const int l15 = lane & 15, lg = lane >> 4;
  const int wr = wid >> 1, wc = wid & 1;
  const int nTn = N >> 7;
  const int cpx = gridDim.x >> 3;                 // grid divisible by 8
  const int swz = ((int)blockIdx.x & 7) * cpx + ((int)blockIdx.x >> 3);
  const int m0 = (swz / nTn) * 128, n0 = (swz % nTn) * 128;
  const ushort* Ag = A + (size_t)m0 * K;
  const ushort* Bg = Bt + (size_t)n0 * K;
  const int coff = (lg ^ ((l15 >> 1) & 3)) * 8;
  const int abase = (wr * 64 + l15) * 32 + coff;
  const int bbase = (wc * 64 + l15) * 32 + coff;
  const int nk = K >> 5;

  f32x4 acc[4][4] = {};

  auto stage_one = [&](const ushort* G, ushort* Ls, int k0) {
#pragma unroll
    for (int i = 0; i < 2; ++i) {
      const int c = i * 256 + tid;                // chunk 0..511 (16B each)
      const int row = c >> 2, cc = c & 3;
      const int scc = cc ^ ((row >> 1) & 3);      // inverse-swizzle the SOURCE
      load_lds16(G + (size_t)row * K + k0 + scc * 8,
                 Ls + (i * 256 + wid * 64) * 8);
    }
  };

#pragma unroll
  for (int t = 0; t < 3; ++t) {
    stage_one(Ag, LA[t], t * 32);
    stage_one(Bg, LB[t], t * 32);
  }
  asm volatile("s_waitcnt vmcnt(8)" ::: "memory");
  __builtin_amdgcn_s_barrier();

  auto ktile = [&](auto VMC, auto STG, int t) {
    constexpr int VM = decltype(VMC)::value;
    constexpr bool STAGE = decltype(STG)::value;
    const int slot = t & 3;
    const ushort* Las = LA[slot];
    const ushort* Lbs = LB[slot];
    short8 afr[4], bfr[4];
#pragma unroll
    for (int n = 0; n < 4; ++n) bfr[n] = *(const short8*)&Lbs[bbase + n * 512];
#pragma unroll
    for (int m = 0; m < 4; ++m) afr[m] = *(const short8*)&Las[abase + m * 512];
    if constexpr (STAGE) {
      stage_one(Ag, LA[(t + 3) & 3], (t + 3) * 32);
      stage_one(Bg, LB[(t + 3) & 3], (t + 3) * 32);
    }
    __builtin_amdgcn_s_setprio(1);
#pragma unroll
    for (int m = 0; m < 4; ++m)
#pragma unroll
      for (int n = 0; n < 4; ++n)
        acc[m][n] = __builtin_amdgcn_mfma_f32_16x16x32_bf16(afr[m], bfr[n], acc[m][n], 0, 0, 0);
    __builtin_amdgcn_s_setprio(0);
    if constexpr (VM == 8)      asm volatile("s_waitcnt vmcnt(8)" ::: "memory");
    else if constexpr (VM == 4) asm volatile("s_waitcnt vmcnt(4)" ::: "memory");
    else if constexpr (VM == 0) asm volatile("s_waitcnt vmcnt(0)" ::: "memory");
    __builtin_amdgcn_s_barrier();
  };

  using tru = std::integral_constant<bool, true>;
  using fal = std::integral_constant<bool, false>;
  for (int t = 0; t + 3 < nk; ++t)
    ktile(std::integral_constant<int, 8>{}, tru{}, t);
  ktile(std::integral_constant<int, 4>{}, fal{}, nk - 3);
  ktile(std::integral_constant<int, 0>{}, fal{}, nk - 2);
  ktile(std::integral_constant<int, -1>{}, fal{}, nk - 1);

#pragma unroll
  for (int m = 0; m < 4; ++m)
#pragma unroll
    for (int n = 0; n < 4; ++n) {
      const int col = n0 + wc * 64 + n * 16 + l15;
      const float bv = bias[col];
#pragma unroll
      for (int r = 0; r < 4; ++r) {
        const int row = m0 + wr * 64 + m * 16 + lg * 4 + r;
        if constexpr (OBF)
          ((ushort*)Cv)[(size_t)row * N + col] = f2bf(acc[m][n][r] + bv);
        else
          ((float*)Cv)[(size_t)row * N + col] = acc[m][n][r] + bv;
      }
    }
}

// ---------------- 256x256 ring-4 bf16 NT GEMM, ONE barrier per K-tile (r17-proven) ----------------
template <bool OBF>
__global__ __launch_bounds__(512, 2) void gemm256(
    const ushort* __restrict__ A, const ushort* __restrict__ Bt,
    const float* __restrict__ bias, void* __restrict__ Cv,
    int M, int N, int K) {
  __shared__ __align__(16) ushort LA[4][8192];   // [slot][256 rows x 32 cols]
  __shared__ __align__(16) ushort LB[4][8192];
  const int tid = threadIdx.x;
  const int wid = tid >> 6, lane = tid & 63;
  const int l15 = lane & 15, lg = lane >> 4;
  const int wr = wid >> 2, wc = wid & 3;
  const int nTn = N >> 8;
  const int cpx = gridDim.x >> 3;                 // grid divisible by 8
  const int swz = ((int)blockIdx.x & 7) * cpx + ((int)blockIdx.x >> 3);
  const int m0 = (swz / nTn) * 256, n0 = (swz % nTn) * 256;
  const ushort* Ag = A + (size_t)m0 * K;
  const ushort* Bg = Bt + (size_t)n0 * K;
  const int coff = (lg ^ ((l15 >> 1) & 3)) * 8;
  const int abase = (wr * 128 + l15) * 32 + coff;
  const int bbase = (wc * 64 + l15) * 32 + coff;
  const int nk = K >> 5;

  f32x4 acc[8][4] = {};

  auto stage_one = [&](const ushort* G, ushort* Ls, int k0) {
#pragma unroll
    for (int i = 0; i < 2; ++i) {
      const int c = i * 512 + tid;                // chunk 0..1023
      const int row = c >> 2, cc = c & 3;
      const int scc = cc ^ ((row >> 1) & 3);      // inverse-swizzle the SOURCE
      load_lds16(G + (size_t)row * K + k0 + scc * 8,
                 Ls + (i * 512 + wid * 64) * 8);
    }
  };

#pragma unroll
  for (int t = 0; t < 3; ++t) {
    stage_one(Ag, LA[t], t * 32);
    stage_one(Bg, LB[t], t * 32);
  }
  asm volatile("s_waitcnt vmcnt(8)" ::: "memory");
  __builtin_amdgcn_s_barrier();

  auto ktile = [&](auto VMC, auto STG, int t) {
    constexpr int VM = decltype(VMC)::value;
    constexpr bool STAGE = decltype(STG)::value;
    const int slot = t & 3;
    const ushort* Las = LA[slot];
    const ushort* Lbs = LB[slot];
    short8 afr[8], bfr[4];
#pragma unroll
    for (int n = 0; n < 4; ++n) bfr[n] = *(const short8*)&Lbs[bbase + n * 512];
#pragma unroll
    for (int m = 0; m < 8; ++m) afr[m] = *(const short8*)&Las[abase + m * 512];
    if constexpr (STAGE) {
      stage_one(Ag, LA[(t + 3) & 3], (t + 3) * 32);
      stage_one(Bg, LB[(t + 3) & 3], (t + 3) * 32);
    }
    __builtin_amdgcn_s_setprio(1);
#pragma unroll
    for (int m = 0; m < 8; ++m)
#pragma unroll
      for (int n = 0; n < 4; ++n)
        acc[m][n] = __builtin_amdgcn_mfma_f32_16x16x32_bf16(afr[m], bfr[n], acc[m][n], 0, 0, 0);
    __builtin_amdgcn_s_setprio(0);
    if constexpr (VM == 8)      asm volatile("s_waitcnt vmcnt(8)" ::: "memory");
    else if constexpr (VM == 4) asm volatile("s_waitcnt vmcnt(4)" ::: "memory");
    else if constexpr (VM == 0) asm volatile("s_waitcnt vmcnt(0)" ::: "memory");
    __builtin_amdgcn_s_barrier();
  };

  using tru = std::integral_constant<bool, true>;
  using fal = std::integral_constant<bool, false>;
  for (int t = 0; t + 3 < nk; ++t)
    ktile(std::integral_constant<int, 8>{}, tru{}, t);
  ktile(std::integral_constant<int, 4>{}, fal{}, nk - 3);
  ktile(std::integral_constant<int, 0>{}, fal{}, nk - 2);
  ktile(std::integral_constant<int, -1>{}, fal{}, nk - 1);

#pragma unroll
  for (int m = 0; m < 8; ++m)
#pragma unroll
    for (int n = 0; n < 4; ++n) {
      const int col = n0 + wc * 64 + n * 16 + l15;
      const float bv = bias[col];
#pragma unroll
      for (int r = 0; r < 4; ++r) {
        const int row = m0 + wr * 128 + m * 16 + lg * 4 + r;
        if constexpr (OBF)
          ((ushort*)Cv)[(size_t)row * N + col] = f2bf(acc[m][n][r] + bv);
        else
          ((float*)Cv)[(size_t)row * N + col] = acc[m][n][r] + bv;
      }
    }
}

// ---------------- causal depthwise conv(K=4) + bias + RoPE, 448-thread blocks ----------------
// 448 = 7 waves; p = tid directly (was (4096,2)x256 with 64 idle lanes/512).
__global__ __launch_bounds__(448) void conv_rope(
    const ushort* __restrict__ qkv, const float* __restrict__ cwT,
    const float* __restrict__ cb, const float* __restrict__ cosT,
    const float* __restrict__ sinT, ushort* __restrict__ Qo,
    ushort* __restrict__ Ko, ushort* __restrict__ Vo) {
  const int token = blockIdx.x;            // b*S + s
  const int s = token & (S_LEN - 1);
  const int p = threadIdx.x;               // 0..447

  auto conv4 = [&](int c0, float out[4]) {
    const float4 bb = *(const float4*)&cb[c0];
    out[0] = bb.x; out[1] = bb.y; out[2] = bb.z; out[3] = bb.w;
#pragma unroll
    for (int j = 0; j < 4; j++) {
      int ss = s - 3 + j;
      if (ss >= 0) {
        ushort4 v = *(const ushort4*)&qkv[(size_t)(token - 3 + j) * QKVD + c0];
        const float4 w = *(const float4*)&cwT[j * QKVD + c0];
        out[0] += bf2f(v.x) * w.x;
        out[1] += bf2f(v.y) * w.y;
        out[2] += bf2f(v.z) * w.z;
        out[3] += bf2f(v.w) * w.w;
      }
    }
  };

  if (p < 256) {                  // Q: h = p>>4, d0 = (p&15)*4; pre-scaled
    const int h = p >> 4, d0 = (p & 15) * 4;
    const int c1 = h * 128 + d0;
    float x1[4], x2[4];
    conv4(c1, x1); conv4(c1 + 64, x2);
    const float4 co = *(const float4*)&cosT[s * 64 + d0];
    const float4 si = *(const float4*)&sinT[s * 64 + d0];
    ushort4 o1, o2v;
    o1.x = f2bf((x1[0] * co.x - x2[0] * si.x) * QSCALE);
    o1.y = f2bf((x1[1] * co.y - x2[1] * si.y) * QSCALE);
    o1.z = f2bf((x1[2] * co.z - x2[2] * si.z) * QSCALE);
    o1.w = f2bf((x1[3] * co.w - x2[3] * si.w) * QSCALE);
    o2v.x = f2bf((x2[0] * co.x + x1[0] * si.x) * QSCALE);
    o2v.y = f2bf((x2[1] * co.y + x1[1] * si.y) * QSCALE);
    o2v.z = f2bf((x2[2] * co.z + x1[2] * si.z) * QSCALE);
    o2v.w = f2bf((x2[3] * co.w + x1[3] * si.w) * QSCALE);
    const size_t base = ((size_t)token * NH + h) * HDIM + d0;
    *(ushort4*)&Qo[base] = o1;
    *(ushort4*)&Qo[base + 64] = o2v;
  } else if (p < 320) {           // K: idx = p-256: h = idx>>4, d0 = (idx&15)*4
    const int idx = p - 256, h = idx >> 4, d0 = (idx & 15) * 4;
    const int c1 = 2048 + h * 128 + d0;
    float x1[4], x2[4];
    conv4(c1, x1); conv4(c1 + 64, x2);
    const float4 co = *(const float4*)&cosT[s * 64 + d0];
    const float4 si = *(const float4*)&sinT[s * 64 + d0];
    ushort4 o1, o2v;
    o1.x = f2bf(x1[0] * co.x - x2[0] * si.x);
    o1.y = f2bf(x1[1] * co.y - x2[1] * si.y);
    o1.z = f2bf(x1[2] * co.z - x2[2] * si.z);
    o1.w = f2bf(x1[3] * co.w - x2[3] * si.w);
    o2v.x = f2bf(x2[0] * co.x + x1[0] * si.x);
    o2v.y = f2bf(x2[1] * co.y + x1[1] * si.y);
    o2v.z = f2bf(x2[2] * co.z + x1[2] * si.z);
    o2v.w = f2bf(x2[3] * co.w + x1[3] * si.w);
    const size_t base = ((size_t)token * NKV + h) * HDIM + d0;
    *(ushort4*)&Ko[base] = o1;
    *(ushort4*)&Ko[base + 64] = o2v;
  } else {                        // V: idx = p-320 in [0,128): c0 = 2560 + idx*4
    const int idx = p - 320;
    const int c0 = 2560 + idx * 4;
    float v[4];
    conv4(c0, v);
    const int hd = idx * 4;
    const int h = hd >> 7, d = hd & 127;
    ushort4 o;
    o.x = f2bf(v[0]); o.y = f2bf(v[1]); o.z = f2bf(v[2]); o.w = f2bf(v[3]);
    *(ushort4*)&Vo[((size_t)token * NKV + h) * HDIM + d] = o;
  }
}

// ---------------- V transpose: Vb[b*S+s][kvh][d] -> Vt[(b*NKV+kvh)*128 + d][s] ----------------
__global__ __launch_bounds__(256) void transpose_v(const ushort* __restrict__ Vb,
                                                   ushort* __restrict__ Vt) {
  __shared__ ushort t[64][65];
  const int tid = threadIdx.x;
  const int s0 = blockIdx.x * 64, d0 = blockIdx.y * 64;
  const int g = blockIdx.z;                       // b*NKV + kvh
  const int b = g >> 2, kvh = g & 3;
#pragma unroll
  for (int p = 0; p < 8; p++) {
    int idx = p * 256 + tid;                      // [0,2048)
    int r = idx >> 5, c2 = (idx & 31) * 2;
    ushort2 v = *(const ushort2*)&Vb[((size_t)(b * S_LEN + s0 + r) * NKV + kvh) * HDIM + d0 + c2];
    t[r][c2] = v.x; t[r][c2 + 1] = v.y;
  }
  __syncthreads();
#pragma unroll
  for (int p = 0; p < 8; p++) {
    int idx = p * 256 + tid;
    int dr = idx >> 5, sc2 = (idx & 31) * 2;
    ushort2 v; v.x = t[sc2][dr]; v.y = t[sc2 + 1][dr];
    *(ushort2*)&Vt[((size_t)g * HDIM + d0 + dr) * S_LEN + s0 + sc2] = v;
  }
}

// ---------------- causal GQA flash attention: K dbuf + single-V + defer-rescale (r23-proven) ----------------
__global__ __launch_bounds__(256, 3) void attn(
    const ushort* __restrict__ Q, const ushort* __restrict__ K,
    const ushort* __restrict__ Vt, ushort* __restrict__ ctx) {
  __shared__ __align__(16) ushort Ks[2][64 * 128];   // [key][d], chunk(16) ^= row&7
  __shared__ __align__(16) ushort Vs[128 * 64];      // [d][key], chunk(8)  ^= d&7
  const int tid = threadIdx.x;
  const int wid = tid >> 6, lane = tid & 63;
  const int l15 = lane & 15, lg = lane >> 4;
  const int bkv = blockIdx.x;                   // b*NKV + kvh; maps 1:1 to an XCD
  const int b = bkv >> 2, kvh = bkv & 3;
  const int h = kvh * 4 + wid;                  // wave = one q-head of the group
  const int qb = (gridDim.y - 1) - blockIdx.y;  // longest blocks dispatch first
  const int q0 = qb * 16;

  const ushort* Kbase  = K  + ((size_t)b * S_LEN * NKV + kvh) * HDIM;
  const ushort* Vtbase = Vt + (size_t)bkv * HDIM * S_LEN;

  short8 qf[4];
#pragma unroll
  for (int kd = 0; kd < 4; kd++)
    qf[kd] = *(const short8*)&Q[(((size_t)(b * S_LEN + q0 + l15)) * NH + h) * HDIM + kd * 32 + lg * 8];

  auto stageK = [&](int tile, int bufi) {
    const int j0t = tile * 64;
#pragma unroll
    for (int p = 0; p < 4; ++p) {
      const int i = wid * 4 + p;                // 0..15
      const int row = i * 4 + (lane >> 4);      // key row 0..63
      const int cs  = (lane & 15) ^ (row & 7);
      load_lds16(Kbase + (size_t)(j0t + row) * (NKV * HDIM) + cs * 8,
                 &Ks[bufi][i * 512]);
    }
  };
  auto stageV = [&](int tile) {
    const int j0t = tile * 64;
#pragma unroll
    for (int p = 0; p < 4; ++p) {
      const int i = wid * 4 + p;                // 0..15
      const int d  = i * 8 + (lane >> 3);       // d row 0..127
      const int cs = (lane & 7) ^ (d & 7);
      load_lds16(Vtbase + (size_t)d * S_LEN + j0t + cs * 8,
                 &Vs[i * 512]);
    }
  };

  f32x4 o2[8] = {};
  float m_run = -3e30f, l_run = 0.f;
  const int ntile = q0 / 64 + 1;
  const int qrow = q0 + l15;

  stageK(0, 0);
  __syncthreads();
  int buf = 0;
  for (int jt = 0; jt < ntile; ++jt) {
    const int j0 = jt * 64;
    if (jt + 1 < ntile) stageK(jt + 1, buf ^ 1);
    stageV(jt);                                  // lands under QK^T+softmax

    f32x4 sa[4] = {};
#pragma unroll
    for (int t = 0; t < 4; ++t) {
      const int r = t * 16 + l15;
#pragma unroll
      for (int kd = 0; kd < 4; ++kd) {
        short8 kf = *(const short8*)&Ks[buf][r * 128 + (((kd * 4 + lg) ^ (r & 7)) * 8)];
        sa[t] = __builtin_amdgcn_mfma_f32_16x16x32_bf16(kf, qf[kd], sa[t], 0, 0, 0);
      }
    }

    float pv[4][4];
    float mx = -3e30f;
#pragma unroll
    for (int t = 0; t < 4; ++t)
#pragma unroll
      for (int r = 0; r < 4; ++r) {
        float v = sa[t][r];
        if (j0 + t * 16 + lg * 4 + r > qrow) v = -3e30f;   // causal mask
        pv[t][r] = v;
        mx = fmaxf(mx, v);
      }
    mx = fmaxf(mx, __shfl_xor(mx, 16));
    mx = fmaxf(mx, __shfl_xor(mx, 32));
    // T13 defer-rescale: skip the O-wide rescale while max growth <= 8
    if (!__all(mx <= m_run + 8.f)) {
      const float mnew = fmaxf(m_run, mx);
      const float fac = fexp2(m_run - mnew);
      m_run = mnew;
      l_run *= fac;
#pragma unroll
      for (int dt = 0; dt < 8; ++dt)
#pragma unroll
        for (int r = 0; r < 4; ++r) o2[dt][r] *= fac;
    }
    float sum = 0.f;
#pragma unroll
    for (int t = 0; t < 4; ++t)
#pragma unroll
      for (int r = 0; r < 4; ++r) {
        float p = fexp2(pv[t][r] - m_run);       // <= 2^8
        pv[t][r] = p;
        sum += p;
      }
    sum += __shfl_xor(sum, 16);
    sum += __shfl_xor(sum, 32);
    l_run += sum;

    unsigned pk[4][2];
#pragma unroll
    for (int t = 0; t < 4; ++t)
#pragma unroll
      for (int p = 0; p < 2; ++p)
        pk[t][p] = cvt_pk_bf16(pv[t][2 * p], pv[t][2 * p + 1]);

    union U8 { unsigned u[4]; short8 s; } pfk[2];
#pragma unroll
    for (int ks = 0; ks < 2; ++ks)
#pragma unroll
      for (int j = 0; j < 4; ++j) {
        const int src = ((lg & 1) * 2 + (j >> 1)) * 16 + l15;
        unsigned v0 = __shfl((int)pk[ks * 2][j & 1], src);
        unsigned v1 = __shfl((int)pk[ks * 2 + 1][j & 1], src);
        pfk[ks].u[j] = (lg >= 2) ? v1 : v0;
      }

    __syncthreads();   // V(jt) writes visible to all waves before PV reads

#pragma unroll
    for (int dt = 0; dt < 8; ++dt) {
      const int d = dt * 16 + l15;
#pragma unroll
      for (int ks = 0; ks < 2; ++ks) {
        short8 vf = *(const short8*)&Vs[d * 64 + (((ks * 4 + lg) ^ (d & 7)) * 8)];
        o2[dt] = __builtin_amdgcn_mfma_f32_16x16x32_bf16(vf, pfk[ks].s, o2[dt], 0, 0, 0);
      }
    }

    __syncthreads();   // V reads done before next stageV; Ks[buf^1] landed
    buf ^= 1;
  }

  const float inv_l = 1.f / l_run;
  const size_t obase = (((size_t)(b * S_LEN + q0 + l15)) * NH + h) * HDIM;
#pragma unroll
  for (int dt = 0; dt < 8; ++dt) {
    ushort4 w;
    w.x = f2bf(o2[dt][0] * inv_l);
    w.y = f2bf(o2[dt][1] * inv_l);
    w.z = f2bf(o2[dt][2] * inv_l);
    w.w = f2bf(o2[dt][3] * inv_l);
    *(ushort4*)&ctx[obase + dt * 16 + lg * 4] = w;
  }
}

// ---------------- launcher ----------------
extern "C" void kernel_launch(void* const* d_in, const int* in_sizes, int n_in,
                              void* d_out, int out_size, void* d_ws, size_t ws_size,
                              hipStream_t stream) {
  const float* x      = (const float*)d_in[0];
  const float* w_in   = (const float*)d_in[1];
  const float* b_in   = (const float*)d_in[2];
  const float* conv_w = (const float*)d_in[3];
  const float* conv_b = (const float*)d_in[4];
  const float* w_out  = (const float*)d_in[5];
  const float* b_out  = (const float*)d_in[6];
  float* out = (float*)d_out;

  char* ws = (char*)d_ws;
  size_t off = 0;
  ushort* xbf  = (ushort*)(ws + off); off += (size_t)4096 * 2048 * 2;  // x bf16; later reused as ctx
  ushort* wibf = (ushort*)(ws + off); off += (size_t)3072 * 2048 * 2;
  ushort* wobf = (ushort*)(ws + off); off += (size_t)2048 * 2048 * 2;
  ushort* qkv  = (ushort*)(ws + off); off += (size_t)4096 * 3072 * 2;  // bf16; dead after conv_rope
  ushort* Qb   = (ushort*)(ws + off); off += (size_t)4096 * 16 * 128 * 2;
  ushort* Kb   = (ushort*)(ws + off); off += (size_t)4096 * 4 * 128 * 2;
  ushort* Vb   = (ushort*)(ws + off); off += (size_t)4096 * 4 * 128 * 2;
  float*  cosT = (float*)(ws + off);  off += (size_t)2048 * 64 * 4;
  float*  sinT = (float*)(ws + off);  off += (size_t)2048 * 64 * 4;
  float*  cwT  = (float*)(ws + off);  off += (size_t)4 * QKVD * 4;     // transposed conv weights
  ushort* Vtb  = (ushort*)qkv;        // alias: transposed V lives in dead qkv buffer (8 MB)

  // 18432 cast + 512 rope + 48 cwT = 18992 blocks, one launch
  prep<<<18992, 256, 0, stream>>>(x, w_in, w_out, conv_w,
                                  xbf, wibf, wobf, cosT, sinT, cwT);

  gemm256<true><<<192, 512, 0, stream>>>(xbf, wibf, b_in, qkv, 4096, 3072, 2048);
  conv_rope<<<4096, 448, 0, stream>>>(qkv, cwT, conv_b, cosT, sinT, Qb, Kb, Vb);
  transpose_v<<<dim3(32, 2, 8), 256, 0, stream>>>(Vb, Vtb);
  attn<<<dim3(8, 128), 256, 0, stream>>>(Qb, Kb, Vtb, xbf);
  gemm128<false><<<512, 256, 0, stream>>>(xbf, wobf, b_out, out, 4096, 2048, 2048);
}

// Round 27
// 197.084 us; speedup vs baseline: 1.1006x; 1.0450x over previous
//
#include <hip/hip_runtime.h>
#include <type_traits>

#define S_LEN 2048
#define BATCH 2
#define EDIM  2048
#define NH    16
#define NKV   4
#define HDIM  128
#define QKVD  3072
// ATT_SCALE * log2(e): folded into Q at conv_rope time -> scores in log2 domain
#define QSCALE 0.12751579107188777f

typedef __attribute__((ext_vector_type(8))) short short8;
typedef __attribute__((ext_vector_type(4))) float f32x4;

__device__ __forceinline__ ushort f2bf(float f) {
  union { float f; unsigned u; } un; un.f = f;
  unsigned u = un.u + 0x7fffu + ((un.u >> 16) & 1u);
  return (ushort)(u >> 16);
}
__device__ __forceinline__ float bf2f(ushort h) {
  union { unsigned u; float f; } un; un.u = ((unsigned)h) << 16;
  return un.f;
}
__device__ __forceinline__ unsigned cvt_pk_bf16(float lo, float hi) {
  unsigned r;
  asm("v_cvt_pk_bf16_f32 %0, %1, %2" : "=v"(r) : "v"(lo), "v"(hi));
  return r;
}
__device__ __forceinline__ float fexp2(float x) { return __builtin_amdgcn_exp2f(x); }

__device__ __forceinline__ void load_lds16(const void* g, void* l) {
  __builtin_amdgcn_global_load_lds((const __attribute__((address_space(1))) void*)g,
                                   (__attribute__((address_space(3))) void*)l,
                                   16, 0, 0);
}

// ---------------- fused prep: f32->bf16 casts + RoPE table + conv-w transpose ----------------
__global__ __launch_bounds__(256) void prep(const float* __restrict__ a,
                                            const float* __restrict__ b,
                                            const float* __restrict__ c,
                                            const float* __restrict__ cw,
                                            ushort* __restrict__ oa,
                                            ushort* __restrict__ ob,
                                            ushort* __restrict__ oc,
                                            float* __restrict__ cosT,
                                            float* __restrict__ sinT,
                                            float* __restrict__ cwT) {
  int i = blockIdx.x * 256 + threadIdx.x;
  if (i < 4718592) {                              // cast sections (float4 each)
    const float* s; ushort* d; int j;
    if (i < 2097152)      { s = a; d = oa; j = i; }
    else if (i < 3670016) { s = b; d = ob; j = i - 2097152; }
    else                  { s = c; d = oc; j = i - 3670016; }
    float4 v = ((const float4*)s)[j];
    ushort4 o;
    o.x = f2bf(v.x); o.y = f2bf(v.y); o.z = f2bf(v.z); o.w = f2bf(v.w);
    ((ushort4*)d)[j] = o;
  } else if (i < 4849664) {                       // RoPE table: S*64 entries
    int k = i - 4718592;
    int s = k >> 6, d = k & 63;
    float inv = expf(-(float)d * 0.14391156831212787f);   // 10000^(-d/64)
    float f = (float)s * inv;
    float sv, cv;
    sincosf(f, &sv, &cv);
    cosT[k] = cv;
    sinT[k] = sv;
  } else {                                        // cw[c][j] -> cwT[j][c], 12288
    int k = i - 4849664;
    int cc = k >> 2, j = k & 3;
    cwT[j * QKVD + cc] = cw[k];
  }
}

// ---------------- 128x128 ring-4 bf16 NT GEMM (r22-proven) ----------------
template <bool OBF>
__global__ __launch_bounds__(256, 2) void gemm128(
    const ushort* __restrict__ A, const ushort* __restrict__ Bt,
    const float* __restrict__ bias, void* __restrict__ Cv,
    int M, int N, int K) {
  __shared__ __align__(16) ushort LA[4][4096];   // [slot][128 rows x 32 cols]
  __shared__ __align__(16) ushort LB[4][4096];
  const int tid = threadIdx.x;
  const int wid = tid >> 6, lane = tid & 63;
  const int l15 = lane & 15, lg = lane >> 4;
  const int wr = wid >> 1, wc = wid & 1;
  const int nTn = N >> 7;
  const int cpx = gridDim.x >> 3;                 // grid divisible by 8
  const int swz = ((int)blockIdx.x & 7) * cpx + ((int)blockIdx.x >> 3);
  const int m0 = (swz / nTn) * 128, n0 = (swz % nTn) * 128;
  const ushort* Ag = A + (size_t)m0 * K;
  const ushort* Bg = Bt + (size_t)n0 * K;
  const int coff = (lg ^ ((l15 >> 1) & 3)) * 8;
  const int abase = (wr * 64 + l15) * 32 + coff;
  const int bbase = (wc * 64 + l15) * 32 + coff;
  const int nk = K >> 5;

  f32x4 acc[4][4] = {};

  auto stage_one = [&](const ushort* G, ushort* Ls, int k0) {
#pragma unroll
    for (int i = 0; i < 2; ++i) {
      const int c = i * 256 + tid;                // chunk 0..511 (16B each)
      const int row = c >> 2, cc = c & 3;
      const int scc = cc ^ ((row >> 1) & 3);      // inverse-swizzle the SOURCE
      load_lds16(G + (size_t)row * K + k0 + scc * 8,
                 Ls + (i * 256 + wid * 64) * 8);
    }
  };

#pragma unroll
  for (int t = 0; t < 3; ++t) {
    stage_one(Ag, LA[t], t * 32);
    stage_one(Bg, LB[t], t * 32);
  }
  asm volatile("s_waitcnt vmcnt(8)" ::: "memory");
  __builtin_amdgcn_s_barrier();

  auto ktile = [&](auto VMC, auto STG, int t) {
    constexpr int VM = decltype(VMC)::value;
    constexpr bool STAGE = decltype(STG)::value;
    const int slot = t & 3;
    const ushort* Las = LA[slot];
    const ushort* Lbs = LB[slot];
    short8 afr[4], bfr[4];
#pragma unroll
    for (int n = 0; n < 4; ++n) bfr[n] = *(const short8*)&Lbs[bbase + n * 512];
#pragma unroll
    for (int m = 0; m < 4; ++m) afr[m] = *(const short8*)&Las[abase + m * 512];
    if constexpr (STAGE) {
      stage_one(Ag, LA[(t + 3) & 3], (t + 3) * 32);
      stage_one(Bg, LB[(t + 3) & 3], (t + 3) * 32);
    }
    __builtin_amdgcn_s_setprio(1);
#pragma unroll
    for (int m = 0; m < 4; ++m)
#pragma unroll
      for (int n = 0; n < 4; ++n)
        acc[m][n] = __builtin_amdgcn_mfma_f32_16x16x32_bf16(afr[m], bfr[n], acc[m][n], 0, 0, 0);
    __builtin_amdgcn_s_setprio(0);
    if constexpr (VM == 8)      asm volatile("s_waitcnt vmcnt(8)" ::: "memory");
    else if constexpr (VM == 4) asm volatile("s_waitcnt vmcnt(4)" ::: "memory");
    else if constexpr (VM == 0) asm volatile("s_waitcnt vmcnt(0)" ::: "memory");
    __builtin_amdgcn_s_barrier();
  };

  using tru = std::integral_constant<bool, true>;
  using fal = std::integral_constant<bool, false>;
  for (int t = 0; t + 3 < nk; ++t)
    ktile(std::integral_constant<int, 8>{}, tru{}, t);
  ktile(std::integral_constant<int, 4>{}, fal{}, nk - 3);
  ktile(std::integral_constant<int, 0>{}, fal{}, nk - 2);
  ktile(std::integral_constant<int, -1>{}, fal{}, nk - 1);

#pragma unroll
  for (int m = 0; m < 4; ++m)
#pragma unroll
    for (int n = 0; n < 4; ++n) {
      const int col = n0 + wc * 64 + n * 16 + l15;
      const float bv = bias[col];
#pragma unroll
      for (int r = 0; r < 4; ++r) {
        const int row = m0 + wr * 64 + m * 16 + lg * 4 + r;
        if constexpr (OBF)
          ((ushort*)Cv)[(size_t)row * N + col] = f2bf(acc[m][n][r] + bv);
        else
          ((float*)Cv)[(size_t)row * N + col] = acc[m][n][r] + bv;
      }
    }
}

// ---------------- 256x256 ring-4 bf16 NT GEMM, ONE barrier per K-tile (r17-proven) ----------------
template <bool OBF>
__global__ __launch_bounds__(512, 2) void gemm256(
    const ushort* __restrict__ A, const ushort* __restrict__ Bt,
    const float* __restrict__ bias, void* __restrict__ Cv,
    int M, int N, int K) {
  __shared__ __align__(16) ushort LA[4][8192];   // [slot][256 rows x 32 cols]
  __shared__ __align__(16) ushort LB[4][8192];
  const int tid = threadIdx.x;
  const int wid = tid >> 6, lane = tid & 63;
  const int l15 = lane & 15, lg = lane >> 4;
  const int wr = wid >> 2, wc = wid & 3;
  const int nTn = N >> 8;
  const int cpx = gridDim.x >> 3;                 // grid divisible by 8
  const int swz = ((int)blockIdx.x & 7) * cpx + ((int)blockIdx.x >> 3);
  const int m0 = (swz / nTn) * 256, n0 = (swz % nTn) * 256;
  const ushort* Ag = A + (size_t)m0 * K;
  const ushort* Bg = Bt + (size_t)n0 * K;
  const int coff = (lg ^ ((l15 >> 1) & 3)) * 8;
  const int abase = (wr * 128 + l15) * 32 + coff;
  const int bbase = (wc * 64 + l15) * 32 + coff;
  const int nk = K >> 5;

  f32x4 acc[8][4] = {};

  auto stage_one = [&](const ushort* G, ushort* Ls, int k0) {
#pragma unroll
    for (int i = 0; i < 2; ++i) {
      const int c = i * 512 + tid;                // chunk 0..1023
      const int row = c >> 2, cc = c & 3;
      const int scc = cc ^ ((row >> 1) & 3);      // inverse-swizzle the SOURCE
      load_lds16(G + (size_t)row * K + k0 + scc * 8,
                 Ls + (i * 512 + wid * 64) * 8);
    }
  };

#pragma unroll
  for (int t = 0; t < 3; ++t) {
    stage_one(Ag, LA[t], t * 32);
    stage_one(Bg, LB[t], t * 32);
  }
  asm volatile("s_waitcnt vmcnt(8)" ::: "memory");
  __builtin_amdgcn_s_barrier();

  auto ktile = [&](auto VMC, auto STG, int t) {
    constexpr int VM = decltype(VMC)::value;
    constexpr bool STAGE = decltype(STG)::value;
    const int slot = t & 3;
    const ushort* Las = LA[slot];
    const ushort* Lbs = LB[slot];
    short8 afr[8], bfr[4];
#pragma unroll
    for (int n = 0; n < 4; ++n) bfr[n] = *(const short8*)&Lbs[bbase + n * 512];
#pragma unroll
    for (int m = 0; m < 8; ++m) afr[m] = *(const short8*)&Las[abase + m * 512];
    if constexpr (STAGE) {
      stage_one(Ag, LA[(t + 3) & 3], (t + 3) * 32);
      stage_one(Bg, LB[(t + 3) & 3], (t + 3) * 32);
    }
    __builtin_amdgcn_s_setprio(1);
#pragma unroll
    for (int m = 0; m < 8; ++m)
#pragma unroll
      for (int n = 0; n < 4; ++n)
        acc[m][n] = __builtin_amdgcn_mfma_f32_16x16x32_bf16(afr[m], bfr[n], acc[m][n], 0, 0, 0);
    __builtin_amdgcn_s_setprio(0);
    if constexpr (VM == 8)      asm volatile("s_waitcnt vmcnt(8)" ::: "memory");
    else if constexpr (VM == 4) asm volatile("s_waitcnt vmcnt(4)" ::: "memory");
    else if constexpr (VM == 0) asm volatile("s_waitcnt vmcnt(0)" ::: "memory");
    __builtin_amdgcn_s_barrier();
  };

  using tru = std::integral_constant<bool, true>;
  using fal = std::integral_constant<bool, false>;
  for (int t = 0; t + 3 < nk; ++t)
    ktile(std::integral_constant<int, 8>{}, tru{}, t);
  ktile(std::integral_constant<int, 4>{}, fal{}, nk - 3);
  ktile(std::integral_constant<int, 0>{}, fal{}, nk - 2);
  ktile(std::integral_constant<int, -1>{}, fal{}, nk - 1);

#pragma unroll
  for (int m = 0; m < 8; ++m)
#pragma unroll
    for (int n = 0; n < 4; ++n) {
      const int col = n0 + wc * 64 + n * 16 + l15;
      const float bv = bias[col];
#pragma unroll
      for (int r = 0; r < 4; ++r) {
        const int row = m0 + wr * 128 + m * 16 + lg * 4 + r;
        if constexpr (OBF)
          ((ushort*)Cv)[(size_t)row * N + col] = f2bf(acc[m][n][r] + bv);
        else
          ((float*)Cv)[(size_t)row * N + col] = acc[m][n][r] + bv;
      }
    }
}

// ---------------- causal conv(K=4) + bias + RoPE, 4 tokens/block via 7-row window ----------------
// grid 1024 x 448 thr. Each thread loads its channels' 7-row window ONCE
// (zero-filled below batch start = reference zero padding) and computes 4
// tokens' convs from registers: qkv read traffic 100 MB -> 44 MB.
__global__ __launch_bounds__(448) void conv_rope(
    const ushort* __restrict__ qkv, const float* __restrict__ cwT,
    const float* __restrict__ cb, const float* __restrict__ cosT,
    const float* __restrict__ sinT, ushort* __restrict__ Qo,
    ushort* __restrict__ Ko, ushort* __restrict__ Vo) {
  const int tok0 = blockIdx.x * 4;         // 4 tokens, same batch (2048 | 4)
  const int s0 = tok0 & (S_LEN - 1);
  const int p = threadIdx.x;               // 0..447

  auto loadw = [&](int c0, ushort4 w[7]) {
#pragma unroll
    for (int k = 0; k < 7; ++k) {
      const int row = s0 - 3 + k;          // in-batch row of window entry k
      if (row >= 0)
        w[k] = *(const ushort4*)&qkv[(size_t)(tok0 - 3 + k) * QKVD + c0];
      else { w[k].x = 0; w[k].y = 0; w[k].z = 0; w[k].w = 0; }
    }
  };
  // conv for token i from window entries i..i+3
  auto convw = [&](const ushort4 w[7], const float4 wt[4], const float4 bb,
                   int i, float out[4]) {
    out[0] = bb.x; out[1] = bb.y; out[2] = bb.z; out[3] = bb.w;
#pragma unroll
    for (int j = 0; j < 4; ++j) {
      const ushort4 v = w[i + j];
      out[0] += bf2f(v.x) * wt[j].x;
      out[1] += bf2f(v.y) * wt[j].y;
      out[2] += bf2f(v.z) * wt[j].z;
      out[3] += bf2f(v.w) * wt[j].w;
    }
  };

  if (p < 256) {                  // Q: h = p>>4, d0 = (p&15)*4; pre-scaled
    const int h = p >> 4, d0 = (p & 15) * 4;
    const int c1 = h * 128 + d0;
    ushort4 wa[7], wb[7];
    loadw(c1, wa); loadw(c1 + 64, wb);
    float4 wtA[4], wtB[4];
#pragma unroll
    for (int j = 0; j < 4; ++j) {
      wtA[j] = *(const float4*)&cwT[j * QKVD + c1];
      wtB[j] = *(const float4*)&cwT[j * QKVD + c1 + 64];
    }
    const float4 bbA = *(const float4*)&cb[c1];
    const float4 bbB = *(const float4*)&cb[c1 + 64];
#pragma unroll
    for (int i = 0; i < 4; ++i) {
      float x1[4], x2[4];
      convw(wa, wtA, bbA, i, x1);
      convw(wb, wtB, bbB, i, x2);
      const float4 co = *(const float4*)&cosT[(s0 + i) * 64 + d0];
      const float4 si = *(const float4*)&sinT[(s0 + i) * 64 + d0];
      ushort4 o1, o2v;
      o1.x = f2bf((x1[0] * co.x - x2[0] * si.x) * QSCALE);
      o1.y = f2bf((x1[1] * co.y - x2[1] * si.y) * QSCALE);
      o1.z = f2bf((x1[2] * co.z - x2[2] * si.z) * QSCALE);
      o1.w = f2bf((x1[3] * co.w - x2[3] * si.w) * QSCALE);
      o2v.x = f2bf((x2[0] * co.x + x1[0] * si.x) * QSCALE);
      o2v.y = f2bf((x2[1] * co.y + x1[1] * si.y) * QSCALE);
      o2v.z = f2bf((x2[2] * co.z + x1[2] * si.z) * QSCALE);
      o2v.w = f2bf((x2[3] * co.w + x1[3] * si.w) * QSCALE);
      const size_t base = ((size_t)(tok0 + i) * NH + h) * HDIM + d0;
      *(ushort4*)&Qo[base] = o1;
      *(ushort4*)&Qo[base + 64] = o2v;
    }
  } else if (p < 320) {           // K: idx = p-256
    const int idx = p - 256, h = idx >> 4, d0 = (idx & 15) * 4;
    const int c1 = 2048 + h * 128 + d0;
    ushort4 wa[7], wb[7];
    loadw(c1, wa); loadw(c1 + 64, wb);
    float4 wtA[4], wtB[4];
#pragma unroll
    for (int j = 0; j < 4; ++j) {
      wtA[j] = *(const float4*)&cwT[j * QKVD + c1];
      wtB[j] = *(const float4*)&cwT[j * QKVD + c1 + 64];
    }
    const float4 bbA = *(const float4*)&cb[c1];
    const float4 bbB = *(const float4*)&cb[c1 + 64];
#pragma unroll
    for (int i = 0; i < 4; ++i) {
      float x1[4], x2[4];
      convw(wa, wtA, bbA, i, x1);
      convw(wb, wtB, bbB, i, x2);
      const float4 co = *(const float4*)&cosT[(s0 + i) * 64 + d0];
      const float4 si = *(const float4*)&sinT[(s0 + i) * 64 + d0];
      ushort4 o1, o2v;
      o1.x = f2bf(x1[0] * co.x - x2[0] * si.x);
      o1.y = f2bf(x1[1] * co.y - x2[1] * si.y);
      o1.z = f2bf(x1[2] * co.z - x2[2] * si.z);
      o1.w = f2bf(x1[3] * co.w - x2[3] * si.w);
      o2v.x = f2bf(x2[0] * co.x + x1[0] * si.x);
      o2v.y = f2bf(x2[1] * co.y + x1[1] * si.y);
      o2v.z = f2bf(x2[2] * co.z + x1[2] * si.z);
      o2v.w = f2bf(x2[3] * co.w + x1[3] * si.w);
      const size_t base = ((size_t)(tok0 + i) * NKV + h) * HDIM + d0;
      *(ushort4*)&Ko[base] = o1;
      *(ushort4*)&Ko[base + 64] = o2v;
    }
  } else {                        // V: idx = p-320 in [0,128)
    const int idx = p - 320;
    const int c0 = 2560 + idx * 4;
    ushort4 wv[7];
    loadw(c0, wv);
    float4 wt[4];
#pragma unroll
    for (int j = 0; j < 4; ++j) wt[j] = *(const float4*)&cwT[j * QKVD + c0];
    const float4 bb = *(const float4*)&cb[c0];
    const int hd = idx * 4;
    const int h = hd >> 7, d = hd & 127;
#pragma unroll
    for (int i = 0; i < 4; ++i) {
      float v[4];
      convw(wv, wt, bb, i, v);
      ushort4 o;
      o.x = f2bf(v[0]); o.y = f2bf(v[1]); o.z = f2bf(v[2]); o.w = f2bf(v[3]);
      *(ushort4*)&Vo[((size_t)(tok0 + i) * NKV + h) * HDIM + d] = o;
    }
  }
}

// ---------------- V transpose: Vb[b*S+s][kvh][d] -> Vt[(b*NKV+kvh)*128 + d][s] ----------------
__global__ __launch_bounds__(256) void transpose_v(const ushort* __restrict__ Vb,
                                                   ushort* __restrict__ Vt) {
  __shared__ ushort t[64][65];
  const int tid = threadIdx.x;
  const int s0 = blockIdx.x * 64, d0 = blockIdx.y * 64;
  const int g = blockIdx.z;                       // b*NKV + kvh
  const int b = g >> 2, kvh = g & 3;
#pragma unroll
  for (int p = 0; p < 8; p++) {
    int idx = p * 256 + tid;                      // [0,2048)
    int r = idx >> 5, c2 = (idx & 31) * 2;
    ushort2 v = *(const ushort2*)&Vb[((size_t)(b * S_LEN + s0 + r) * NKV + kvh) * HDIM + d0 + c2];
    t[r][c2] = v.x; t[r][c2 + 1] = v.y;
  }
  __syncthreads();
#pragma unroll
  for (int p = 0; p < 8; p++) {
    int idx = p * 256 + tid;
    int dr = idx >> 5, sc2 = (idx & 31) * 2;
    ushort2 v; v.x = t[sc2][dr]; v.y = t[sc2 + 1][dr];
    *(ushort2*)&Vt[((size_t)g * HDIM + d0 + dr) * S_LEN + s0 + sc2] = v;
  }
}

// ---------------- causal GQA flash attention: K dbuf + single-V + defer-rescale (r23-proven) ----------------
__global__ __launch_bounds__(256, 3) void attn(
    const ushort* __restrict__ Q, const ushort* __restrict__ K,
    const ushort* __restrict__ Vt, ushort* __restrict__ ctx) {
  __shared__ __align__(16) ushort Ks[2][64 * 128];   // [key][d], chunk(16) ^= row&7
  __shared__ __align__(16) ushort Vs[128 * 64];      // [d][key], chunk(8)  ^= d&7
  const int tid = threadIdx.x;
  const int wid = tid >> 6, lane = tid & 63;
  const int l15 = lane & 15, lg = lane >> 4;
  const int bkv = blockIdx.x;                   // b*NKV + kvh; maps 1:1 to an XCD
  const int b = bkv >> 2, kvh = bkv & 3;
  const int h = kvh * 4 + wid;                  // wave = one q-head of the group
  const int qb = (gridDim.y - 1) - blockIdx.y;  // longest blocks dispatch first
  const int q0 = qb * 16;

  const ushort* Kbase  = K  + ((size_t)b * S_LEN * NKV + kvh) * HDIM;
  const ushort* Vtbase = Vt + (size_t)bkv * HDIM * S_LEN;

  short8 qf[4];
#pragma unroll
  for (int kd = 0; kd < 4; kd++)
    qf[kd] = *(const short8*)&Q[(((size_t)(b * S_LEN + q0 + l15)) * NH + h) * HDIM + kd * 32 + lg * 8];

  auto stageK = [&](int tile, int bufi) {
    const int j0t = tile * 64;
#pragma unroll
    for (int p = 0; p < 4; ++p) {
      const int i = wid * 4 + p;                // 0..15
      const int row = i * 4 + (lane >> 4);      // key row 0..63
      const int cs  = (lane & 15) ^ (row & 7);
      load_lds16(Kbase + (size_t)(j0t + row) * (NKV * HDIM) + cs * 8,
                 &Ks[bufi][i * 512]);
    }
  };
  auto stageV = [&](int tile) {
    const int j0t = tile * 64;
#pragma unroll
    for (int p = 0; p < 4; ++p) {
      const int i = wid * 4 + p;                // 0..15
      const int d  = i * 8 + (lane >> 3);       // d row 0..127
      const int cs = (lane & 7) ^ (d & 7);
      load_lds16(Vtbase + (size_t)d * S_LEN + j0t + cs * 8,
                 &Vs[i * 512]);
    }
  };

  f32x4 o2[8] = {};
  float m_run = -3e30f, l_run = 0.f;
  const int ntile = q0 / 64 + 1;
  const int qrow = q0 + l15;

  stageK(0, 0);
  __syncthreads();
  int buf = 0;
  for (int jt = 0; jt < ntile; ++jt) {
    const int j0 = jt * 64;
    if (jt + 1 < ntile) stageK(jt + 1, buf ^ 1);
    stageV(jt);                                  // lands under QK^T+softmax

    f32x4 sa[4] = {};
#pragma unroll
    for (int t = 0; t < 4; ++t) {
      const int r = t * 16 + l15;
#pragma unroll
      for (int kd = 0; kd < 4; ++kd) {
        short8 kf = *(const short8*)&Ks[buf][r * 128 + (((kd * 4 + lg) ^ (r & 7)) * 8)];
        sa[t] = __builtin_amdgcn_mfma_f32_16x16x32_bf16(kf, qf[kd], sa[t], 0, 0, 0);
      }
    }

    float pv[4][4];
    float mx = -3e30f;
#pragma unroll
    for (int t = 0; t < 4; ++t)
#pragma unroll
      for (int r = 0; r < 4; ++r) {
        float v = sa[t][r];
        if (j0 + t * 16 + lg * 4 + r > qrow) v = -3e30f;   // causal mask
        pv[t][r] = v;
        mx = fmaxf(mx, v);
      }
    mx = fmaxf(mx, __shfl_xor(mx, 16));
    mx = fmaxf(mx, __shfl_xor(mx, 32));
    // T13 defer-rescale: skip the O-wide rescale while max growth <= 8
    if (!__all(mx <= m_run + 8.f)) {
      const float mnew = fmaxf(m_run, mx);
      const float fac = fexp2(m_run - mnew);
      m_run = mnew;
      l_run *= fac;
#pragma unroll
      for (int dt = 0; dt < 8; ++dt)
#pragma unroll
        for (int r = 0; r < 4; ++r) o2[dt][r] *= fac;
    }
    float sum = 0.f;
#pragma unroll
    for (int t = 0; t < 4; ++t)
#pragma unroll
      for (int r = 0; r < 4; ++r) {
        float p = fexp2(pv[t][r] - m_run);       // <= 2^8
        pv[t][r] = p;
        sum += p;
      }
    sum += __shfl_xor(sum, 16);
    sum += __shfl_xor(sum, 32);
    l_run += sum;

    unsigned pk[4][2];
#pragma unroll
    for (int t = 0; t < 4; ++t)
#pragma unroll
      for (int p = 0; p < 2; ++p)
        pk[t][p] = cvt_pk_bf16(pv[t][2 * p], pv[t][2 * p + 1]);

    union U8 { unsigned u[4]; short8 s; } pfk[2];
#pragma unroll
    for (int ks = 0; ks < 2; ++ks)
#pragma unroll
      for (int j = 0; j < 4; ++j) {
        const int src = ((lg & 1) * 2 + (j >> 1)) * 16 + l15;
        unsigned v0 = __shfl((int)pk[ks * 2][j & 1], src);
        unsigned v1 = __shfl((int)pk[ks * 2 + 1][j & 1], src);
        pfk[ks].u[j] = (lg >= 2) ? v1 : v0;
      }

    __syncthreads();   // V(jt) writes visible to all waves before PV reads

#pragma unroll
    for (int dt = 0; dt < 8; ++dt) {
      const int d = dt * 16 + l15;
#pragma unroll
      for (int ks = 0; ks < 2; ++ks) {
        short8 vf = *(const short8*)&Vs[d * 64 + (((ks * 4 + lg) ^ (d & 7)) * 8)];
        o2[dt] = __builtin_amdgcn_mfma_f32_16x16x32_bf16(vf, pfk[ks].s, o2[dt], 0, 0, 0);
      }
    }

    __syncthreads();   // V reads done before next stageV; Ks[buf^1] landed
    buf ^= 1;
  }

  const float inv_l = 1.f / l_run;
  const size_t obase = (((size_t)(b * S_LEN + q0 + l15)) * NH + h) * HDIM;
#pragma unroll
  for (int dt = 0; dt < 8; ++dt) {
    ushort4 w;
    w.x = f2bf(o2[dt][0] * inv_l);
    w.y = f2bf(o2[dt][1] * inv_l);
    w.z = f2bf(o2[dt][2] * inv_l);
    w.w = f2bf(o2[dt][3] * inv_l);
    *(ushort4*)&ctx[obase + dt * 16 + lg * 4] = w;
  }
}

// ---------------- launcher ----------------
extern "C" void kernel_launch(void* const* d_in, const int* in_sizes, int n_in,
                              void* d_out, int out_size, void* d_ws, size_t ws_size,
                              hipStream_t stream) {
  const float* x      = (const float*)d_in[0];
  const float* w_in   = (const float*)d_in[1];
  const float* b_in   = (const float*)d_in[2];
  const float* conv_w = (const float*)d_in[3];
  const float* conv_b = (const float*)d_in[4];
  const float* w_out  = (const float*)d_in[5];
  const float* b_out  = (const float*)d_in[6];
  float* out = (float*)d_out;

  char* ws = (char*)d_ws;
  size_t off = 0;
  ushort* xbf  = (ushort*)(ws + off); off += (size_t)4096 * 2048 * 2;  // x bf16; later reused as ctx
  ushort* wibf = (ushort*)(ws + off); off += (size_t)3072 * 2048 * 2;
  ushort* wobf = (ushort*)(ws + off); off += (size_t)2048 * 2048 * 2;
  ushort* qkv  = (ushort*)(ws + off); off += (size_t)4096 * 3072 * 2;  // bf16; dead after conv_rope
  ushort* Qb   = (ushort*)(ws + off); off += (size_t)4096 * 16 * 128 * 2;
  ushort* Kb   = (ushort*)(ws + off); off += (size_t)4096 * 4 * 128 * 2;
  ushort* Vb   = (ushort*)(ws + off); off += (size_t)4096 * 4 * 128 * 2;
  float*  cosT = (float*)(ws + off);  off += (size_t)2048 * 64 * 4;
  float*  sinT = (float*)(ws + off);  off += (size_t)2048 * 64 * 4;
  float*  cwT  = (float*)(ws + off);  off += (size_t)4 * QKVD * 4;     // transposed conv weights
  ushort* Vtb  = (ushort*)qkv;        // alias: transposed V lives in dead qkv buffer (8 MB)

  // 18432 cast + 512 rope + 48 cwT = 18992 blocks, one launch
  prep<<<18992, 256, 0, stream>>>(x, w_in, w_out, conv_w,
                                  xbf, wibf, wobf, cosT, sinT, cwT);

  gemm256<true><<<192, 512, 0, stream>>>(xbf, wibf, b_in, qkv, 4096, 3072, 2048);
  conv_rope<<<1024, 448, 0, stream>>>(qkv, cwT, conv_b, cosT, sinT, Qb, Kb, Vb);
  transpose_v<<<dim3(32, 2, 8), 256, 0, stream>>>(Vb, Vtb);
  attn<<<dim3(8, 128), 256, 0, stream>>>(Qb, Kb, Vtb, xbf);
  gemm128<false><<<512, 256, 0, stream>>>(xbf, wobf, b_out, out, 4096, 2048, 2048);
}

// Round 28
// 194.580 us; speedup vs baseline: 1.1147x; 1.0129x over previous
//
#include <hip/hip_runtime.h>
#include <type_traits>

#define S_LEN 2048
#define BATCH 2
#define EDIM  2048
#define NH    16
#define NKV   4
#define HDIM  128
#define QKVD  3072
// ATT_SCALE * log2(e): folded into Q at conv_rope time -> scores in log2 domain
#define QSCALE 0.12751579107188777f

typedef __attribute__((ext_vector_type(8))) short short8;
typedef __attribute__((ext_vector_type(4))) float f32x4;

__device__ __forceinline__ ushort f2bf(float f) {
  union { float f; unsigned u; } un; un.f = f;
  unsigned u = un.u + 0x7fffu + ((un.u >> 16) & 1u);
  return (ushort)(u >> 16);
}
__device__ __forceinline__ float bf2f(ushort h) {
  union { unsigned u; float f; } un; un.u = ((unsigned)h) << 16;
  return un.f;
}
__device__ __forceinline__ unsigned cvt_pk_bf16(float lo, float hi) {
  unsigned r;
  asm("v_cvt_pk_bf16_f32 %0, %1, %2" : "=v"(r) : "v"(lo), "v"(hi));
  return r;
}
__device__ __forceinline__ float fexp2(float x) { return __builtin_amdgcn_exp2f(x); }

__device__ __forceinline__ void load_lds16(const void* g, void* l) {
  __builtin_amdgcn_global_load_lds((const __attribute__((address_space(1))) void*)g,
                                   (__attribute__((address_space(3))) void*)l,
                                   16, 0, 0);
}

// ---------------- fused prep: f32->bf16 casts + RoPE table + conv-w transpose ----------------
__global__ __launch_bounds__(256) void prep(const float* __restrict__ a,
                                            const float* __restrict__ b,
                                            const float* __restrict__ c,
                                            const float* __restrict__ cw,
                                            ushort* __restrict__ oa,
                                            ushort* __restrict__ ob,
                                            ushort* __restrict__ oc,
                                            float* __restrict__ cosT,
                                            float* __restrict__ sinT,
                                            float* __restrict__ cwT) {
  int i = blockIdx.x * 256 + threadIdx.x;
  if (i < 4718592) {                              // cast sections (float4 each)
    const float* s; ushort* d; int j;
    if (i < 2097152)      { s = a; d = oa; j = i; }
    else if (i < 3670016) { s = b; d = ob; j = i - 2097152; }
    else                  { s = c; d = oc; j = i - 3670016; }
    float4 v = ((const float4*)s)[j];
    ushort4 o;
    o.x = f2bf(v.x); o.y = f2bf(v.y); o.z = f2bf(v.z); o.w = f2bf(v.w);
    ((ushort4*)d)[j] = o;
  } else if (i < 4849664) {                       // RoPE table: S*64 entries
    int k = i - 4718592;
    int s = k >> 6, d = k & 63;
    float inv = expf(-(float)d * 0.14391156831212787f);   // 10000^(-d/64)
    float f = (float)s * inv;
    float sv, cv;
    sincosf(f, &sv, &cv);
    cosT[k] = cv;
    sinT[k] = sv;
  } else {                                        // cw[c][j] -> cwT[j][c], 12288
    int k = i - 4849664;
    int cc = k >> 2, j = k & 3;
    cwT[j * QKVD + cc] = cw[k];
  }
}

// ---------------- 128x128 ring-4 bf16 NT GEMM (r22-proven) ----------------
template <bool OBF>
__global__ __launch_bounds__(256, 2) void gemm128(
    const ushort* __restrict__ A, const ushort* __restrict__ Bt,
    const float* __restrict__ bias, void* __restrict__ Cv,
    int M, int N, int K) {
  __shared__ __align__(16) ushort LA[4][4096];   // [slot][128 rows x 32 cols]
  __shared__ __align__(16) ushort LB[4][4096];
  const int tid = threadIdx.x;
  const int wid = tid >> 6, lane = tid & 63;
  const int l15 = lane & 15, lg = lane >> 4;
  const int wr = wid >> 1, wc = wid & 1;
  const int nTn = N >> 7;
  const int cpx = gridDim.x >> 3;                 // grid divisible by 8
  const int swz = ((int)blockIdx.x & 7) * cpx + ((int)blockIdx.x >> 3);
  const int m0 = (swz / nTn) * 128, n0 = (swz % nTn) * 128;
  const ushort* Ag = A + (size_t)m0 * K;
  const ushort* Bg = Bt + (size_t)n0 * K;
  const int coff = (lg ^ ((l15 >> 1) & 3)) * 8;
  const int abase = (wr * 64 + l15) * 32 + coff;
  const int bbase = (wc * 64 + l15) * 32 + coff;
  const int nk = K >> 5;

  f32x4 acc[4][4] = {};

  auto stage_one = [&](const ushort* G, ushort* Ls, int k0) {
#pragma unroll
    for (int i = 0; i < 2; ++i) {
      const int c = i * 256 + tid;                // chunk 0..511 (16B each)
      const int row = c >> 2, cc = c & 3;
      const int scc = cc ^ ((row >> 1) & 3);      // inverse-swizzle the SOURCE
      load_lds16(G + (size_t)row * K + k0 + scc * 8,
                 Ls + (i * 256 + wid * 64) * 8);
    }
  };

#pragma unroll
  for (int t = 0; t < 3; ++t) {
    stage_one(Ag, LA[t], t * 32);
    stage_one(Bg, LB[t], t * 32);
  }
  asm volatile("s_waitcnt vmcnt(8)" ::: "memory");
  __builtin_amdgcn_s_barrier();

  auto ktile = [&](auto VMC, auto STG, int t) {
    constexpr int VM = decltype(VMC)::value;
    constexpr bool STAGE = decltype(STG)::value;
    const int slot = t & 3;
    const ushort* Las = LA[slot];
    const ushort* Lbs = LB[slot];
    short8 afr[4], bfr[4];
#pragma unroll
    for (int n = 0; n < 4; ++n) bfr[n] = *(const short8*)&Lbs[bbase + n * 512];
#pragma unroll
    for (int m = 0; m < 4; ++m) afr[m] = *(const short8*)&Las[abase + m * 512];
    if constexpr (STAGE) {
      stage_one(Ag, LA[(t + 3) & 3], (t + 3) * 32);
      stage_one(Bg, LB[(t + 3) & 3], (t + 3) * 32);
    }
    __builtin_amdgcn_s_setprio(1);
#pragma unroll
    for (int m = 0; m < 4; ++m)
#pragma unroll
      for (int n = 0; n < 4; ++n)
        acc[m][n] = __builtin_amdgcn_mfma_f32_16x16x32_bf16(afr[m], bfr[n], acc[m][n], 0, 0, 0);
    __builtin_amdgcn_s_setprio(0);
    if constexpr (VM == 8)      asm volatile("s_waitcnt vmcnt(8)" ::: "memory");
    else if constexpr (VM == 4) asm volatile("s_waitcnt vmcnt(4)" ::: "memory");
    else if constexpr (VM == 0) asm volatile("s_waitcnt vmcnt(0)" ::: "memory");
    __builtin_amdgcn_s_barrier();
  };

  using tru = std::integral_constant<bool, true>;
  using fal = std::integral_constant<bool, false>;
  for (int t = 0; t + 3 < nk; ++t)
    ktile(std::integral_constant<int, 8>{}, tru{}, t);
  ktile(std::integral_constant<int, 4>{}, fal{}, nk - 3);
  ktile(std::integral_constant<int, 0>{}, fal{}, nk - 2);
  ktile(std::integral_constant<int, -1>{}, fal{}, nk - 1);

#pragma unroll
  for (int m = 0; m < 4; ++m)
#pragma unroll
    for (int n = 0; n < 4; ++n) {
      const int col = n0 + wc * 64 + n * 16 + l15;
      const float bv = bias[col];
#pragma unroll
      for (int r = 0; r < 4; ++r) {
        const int row = m0 + wr * 64 + m * 16 + lg * 4 + r;
        if constexpr (OBF)
          ((ushort*)Cv)[(size_t)row * N + col] = f2bf(acc[m][n][r] + bv);
        else
          ((float*)Cv)[(size_t)row * N + col] = acc[m][n][r] + bv;
      }
    }
}

// ---------------- 256x192 ring-4 bf16 NT GEMM: 256 blocks = full CU fill ----------------
// Same proven ring-4/1-barrier schedule; 8 waves (2Mx4N), wave tile 128x48.
// B staged by waves 0-5 only (768 chunks); per-wave counted vmcnt (waves 0-5:
// 4 loads/tile -> 8/4/0; waves 6-7: 2 -> 4/2/0, safe under branch OR exec-mask).
template <bool OBF>
__global__ __launch_bounds__(512, 2) void gemmA(
    const ushort* __restrict__ A, const ushort* __restrict__ Bt,
    const float* __restrict__ bias, void* __restrict__ Cv,
    int M, int N, int K) {
  __shared__ __align__(16) ushort LA[4][8192];   // [slot][256 x 32]
  __shared__ __align__(16) ushort LB[4][6144];   // [slot][192 x 32]
  const int tid = threadIdx.x;
  const int wid = tid >> 6, lane = tid & 63;
  const int l15 = lane & 15, lg = lane >> 4;
  const int wr = wid >> 2, wc = wid & 3;
  const int cpx = gridDim.x >> 3;                 // 256 blocks -> 32
  const int swz = ((int)blockIdx.x & 7) * cpx + ((int)blockIdx.x >> 3);
  const int m0 = (swz >> 4) * 256, n0 = (swz & 15) * 192;   // 16 x 16 tiles
  const ushort* Ag = A + (size_t)m0 * K;
  const ushort* Bg = Bt + (size_t)n0 * K;
  const int coff = (lg ^ ((l15 >> 1) & 3)) * 8;
  const int abase = (wr * 128 + l15) * 32 + coff;
  const int bbase = (wc * 48 + l15) * 32 + coff;
  const int nk = K >> 5;
  const bool wlo = (wid < 6);                     // wave-uniform

  f32x4 acc[8][3] = {};

  auto stageA = [&](int slot, int k0) {
#pragma unroll
    for (int i = 0; i < 2; ++i) {
      const int c = i * 512 + tid;                // 1024 chunks
      const int row = c >> 2, cc = c & 3;
      const int scc = cc ^ ((row >> 1) & 3);
      load_lds16(Ag + (size_t)row * K + k0 + scc * 8,
                 &LA[slot][(i * 512 + wid * 64) * 8]);
    }
  };
  auto stageB = [&](int slot, int k0) {
    if (wlo) {                                    // waves 0-5: 768 chunks
#pragma unroll
      for (int i = 0; i < 2; ++i) {
        const int c = i * 384 + tid;
        const int row = c >> 2, cc = c & 3;
        const int scc = cc ^ ((row >> 1) & 3);
        load_lds16(Bg + (size_t)row * K + k0 + scc * 8,
                   &LB[slot][(i * 384 + wid * 64) * 8]);
      }
    }
  };

#pragma unroll
  for (int t = 0; t < 3; ++t) {
    stageA(t, t * 32);
    stageB(t, t * 32);
  }
  if (wlo) asm volatile("s_waitcnt vmcnt(8)" ::: "memory");
  else     asm volatile("s_waitcnt vmcnt(4)" ::: "memory");
  __builtin_amdgcn_s_barrier();

  auto ktile = [&](auto VMC, auto STG, int t) {
    constexpr int VM = decltype(VMC)::value;      // 2=steady,1=drain1,0=drain0,-1=none
    constexpr bool STAGE = decltype(STG)::value;
    const int slot = t & 3;
    const ushort* Las = LA[slot];
    const ushort* Lbs = LB[slot];
    short8 afr[8], bfr[3];
#pragma unroll
    for (int n = 0; n < 3; ++n) bfr[n] = *(const short8*)&Lbs[bbase + n * 512];
#pragma unroll
    for (int m = 0; m < 8; ++m) afr[m] = *(const short8*)&Las[abase + m * 512];
    if constexpr (STAGE) {
      stageA((t + 3) & 3, (t + 3) * 32);          // slot last read at tile t-1
      stageB((t + 3) & 3, (t + 3) * 32);
    }
    __builtin_amdgcn_s_setprio(1);
#pragma unroll
    for (int m = 0; m < 8; ++m)
#pragma unroll
      for (int n = 0; n < 3; ++n)
        acc[m][n] = __builtin_amdgcn_mfma_f32_16x16x32_bf16(afr[m], bfr[n], acc[m][n], 0, 0, 0);
    __builtin_amdgcn_s_setprio(0);
    if constexpr (VM == 2) {
      if (wlo) asm volatile("s_waitcnt vmcnt(8)" ::: "memory");
      else     asm volatile("s_waitcnt vmcnt(4)" ::: "memory");
    } else if constexpr (VM == 1) {
      if (wlo) asm volatile("s_waitcnt vmcnt(4)" ::: "memory");
      else     asm volatile("s_waitcnt vmcnt(2)" ::: "memory");
    } else if constexpr (VM == 0) {
      asm volatile("s_waitcnt vmcnt(0)" ::: "memory");
    }
    __builtin_amdgcn_s_barrier();
  };

  using tru = std::integral_constant<bool, true>;
  using fal = std::integral_constant<bool, false>;
  for (int t = 0; t + 3 < nk; ++t)
    ktile(std::integral_constant<int, 2>{}, tru{}, t);     // steady: never drain to 0
  ktile(std::integral_constant<int, 1>{}, fal{}, nk - 3);  // drain
  ktile(std::integral_constant<int, 0>{}, fal{}, nk - 2);
  ktile(std::integral_constant<int, -1>{}, fal{}, nk - 1);

#pragma unroll
  for (int m = 0; m < 8; ++m)
#pragma unroll
    for (int n = 0; n < 3; ++n) {
      const int col = n0 + wc * 48 + n * 16 + l15;
      const float bv = bias[col];
#pragma unroll
      for (int r = 0; r < 4; ++r) {
        const int row = m0 + wr * 128 + m * 16 + lg * 4 + r;
        if constexpr (OBF)
          ((ushort*)Cv)[(size_t)row * N + col] = f2bf(acc[m][n][r] + bv);
        else
          ((float*)Cv)[(size_t)row * N + col] = acc[m][n][r] + bv;
      }
    }
}

// ---------------- causal conv(K=4) + bias + RoPE, 4 tokens/block via 7-row window ----------------
__global__ __launch_bounds__(448) void conv_rope(
    const ushort* __restrict__ qkv, const float* __restrict__ cwT,
    const float* __restrict__ cb, const float* __restrict__ cosT,
    const float* __restrict__ sinT, ushort* __restrict__ Qo,
    ushort* __restrict__ Ko, ushort* __restrict__ Vo) {
  const int tok0 = blockIdx.x * 4;         // 4 tokens, same batch (2048 | 4)
  const int s0 = tok0 & (S_LEN - 1);
  const int p = threadIdx.x;               // 0..447

  auto loadw = [&](int c0, ushort4 w[7]) {
#pragma unroll
    for (int k = 0; k < 7; ++k) {
      const int row = s0 - 3 + k;          // in-batch row of window entry k
      if (row >= 0)
        w[k] = *(const ushort4*)&qkv[(size_t)(tok0 - 3 + k) * QKVD + c0];
      else { w[k].x = 0; w[k].y = 0; w[k].z = 0; w[k].w = 0; }
    }
  };
  auto convw = [&](const ushort4 w[7], const float4 wt[4], const float4 bb,
                   int i, float out[4]) {
    out[0] = bb.x; out[1] = bb.y; out[2] = bb.z; out[3] = bb.w;
#pragma unroll
    for (int j = 0; j < 4; ++j) {
      const ushort4 v = w[i + j];
      out[0] += bf2f(v.x) * wt[j].x;
      out[1] += bf2f(v.y) * wt[j].y;
      out[2] += bf2f(v.z) * wt[j].z;
      out[3] += bf2f(v.w) * wt[j].w;
    }
  };

  if (p < 256) {                  // Q: h = p>>4, d0 = (p&15)*4; pre-scaled
    const int h = p >> 4, d0 = (p & 15) * 4;
    const int c1 = h * 128 + d0;
    ushort4 wa[7], wb[7];
    loadw(c1, wa); loadw(c1 + 64, wb);
    float4 wtA[4], wtB[4];
#pragma unroll
    for (int j = 0; j < 4; ++j) {
      wtA[j] = *(const float4*)&cwT[j * QKVD + c1];
      wtB[j] = *(const float4*)&cwT[j * QKVD + c1 + 64];
    }
    const float4 bbA = *(const float4*)&cb[c1];
    const float4 bbB = *(const float4*)&cb[c1 + 64];
#pragma unroll
    for (int i = 0; i < 4; ++i) {
      float x1[4], x2[4];
      convw(wa, wtA, bbA, i, x1);
      convw(wb, wtB, bbB, i, x2);
      const float4 co = *(const float4*)&cosT[(s0 + i) * 64 + d0];
      const float4 si = *(const float4*)&sinT[(s0 + i) * 64 + d0];
      ushort4 o1, o2v;
      o1.x = f2bf((x1[0] * co.x - x2[0] * si.x) * QSCALE);
      o1.y = f2bf((x1[1] * co.y - x2[1] * si.y) * QSCALE);
      o1.z = f2bf((x1[2] * co.z - x2[2] * si.z) * QSCALE);
      o1.w = f2bf((x1[3] * co.w - x2[3] * si.w) * QSCALE);
      o2v.x = f2bf((x2[0] * co.x + x1[0] * si.x) * QSCALE);
      o2v.y = f2bf((x2[1] * co.y + x1[1] * si.y) * QSCALE);
      o2v.z = f2bf((x2[2] * co.z + x1[2] * si.z) * QSCALE);
      o2v.w = f2bf((x2[3] * co.w + x1[3] * si.w) * QSCALE);
      const size_t base = ((size_t)(tok0 + i) * NH + h) * HDIM + d0;
      *(ushort4*)&Qo[base] = o1;
      *(ushort4*)&Qo[base + 64] = o2v;
    }
  } else if (p < 320) {           // K: idx = p-256
    const int idx = p - 256, h = idx >> 4, d0 = (idx & 15) * 4;
    const int c1 = 2048 + h * 128 + d0;
    ushort4 wa[7], wb[7];
    loadw(c1, wa); loadw(c1 + 64, wb);
    float4 wtA[4], wtB[4];
#pragma unroll
    for (int j = 0; j < 4; ++j) {
      wtA[j] = *(const float4*)&cwT[j * QKVD + c1];
      wtB[j] = *(const float4*)&cwT[j * QKVD + c1 + 64];
    }
    const float4 bbA = *(const float4*)&cb[c1];
    const float4 bbB = *(const float4*)&cb[c1 + 64];
#pragma unroll
    for (int i = 0; i < 4; ++i) {
      float x1[4], x2[4];
      convw(wa, wtA, bbA, i, x1);
      convw(wb, wtB, bbB, i, x2);
      const float4 co = *(const float4*)&cosT[(s0 + i) * 64 + d0];
      const float4 si = *(const float4*)&sinT[(s0 + i) * 64 + d0];
      ushort4 o1, o2v;
      o1.x = f2bf(x1[0] * co.x - x2[0] * si.x);
      o1.y = f2bf(x1[1] * co.y - x2[1] * si.y);
      o1.z = f2bf(x1[2] * co.z - x2[2] * si.z);
      o1.w = f2bf(x1[3] * co.w - x2[3] * si.w);
      o2v.x = f2bf(x2[0] * co.x + x1[0] * si.x);
      o2v.y = f2bf(x2[1] * co.y + x1[1] * si.y);
      o2v.z = f2bf(x2[2] * co.z + x1[2] * si.z);
      o2v.w = f2bf(x2[3] * co.w + x1[3] * si.w);
      const size_t base = ((size_t)(tok0 + i) * NKV + h) * HDIM + d0;
      *(ushort4*)&Ko[base] = o1;
      *(ushort4*)&Ko[base + 64] = o2v;
    }
  } else {                        // V: idx = p-320 in [0,128)
    const int idx = p - 320;
    const int c0 = 2560 + idx * 4;
    ushort4 wv[7];
    loadw(c0, wv);
    float4 wt[4];
#pragma unroll
    for (int j = 0; j < 4; ++j) wt[j] = *(const float4*)&cwT[j * QKVD + c0];
    const float4 bb = *(const float4*)&cb[c0];
    const int hd = idx * 4;
    const int h = hd >> 7, d = hd & 127;
#pragma unroll
    for (int i = 0; i < 4; ++i) {
      float v[4];
      convw(wv, wt, bb, i, v);
      ushort4 o;
      o.x = f2bf(v[0]); o.y = f2bf(v[1]); o.z = f2bf(v[2]); o.w = f2bf(v[3]);
      *(ushort4*)&Vo[((size_t)(tok0 + i) * NKV + h) * HDIM + d] = o;
    }
  }
}

// ---------------- V transpose: Vb[b*S+s][kvh][d] -> Vt[(b*NKV+kvh)*128 + d][s] ----------------
__global__ __launch_bounds__(256) void transpose_v(const ushort* __restrict__ Vb,
                                                   ushort* __restrict__ Vt) {
  __shared__ ushort t[64][65];
  const int tid = threadIdx.x;
  const int s0 = blockIdx.x * 64, d0 = blockIdx.y * 64;
  const int g = blockIdx.z;                       // b*NKV + kvh
  const int b = g >> 2, kvh = g & 3;
#pragma unroll
  for (int p = 0; p < 8; p++) {
    int idx = p * 256 + tid;                      // [0,2048)
    int r = idx >> 5, c2 = (idx & 31) * 2;
    ushort2 v = *(const ushort2*)&Vb[((size_t)(b * S_LEN + s0 + r) * NKV + kvh) * HDIM + d0 + c2];
    t[r][c2] = v.x; t[r][c2 + 1] = v.y;
  }
  __syncthreads();
#pragma unroll
  for (int p = 0; p < 8; p++) {
    int idx = p * 256 + tid;
    int dr = idx >> 5, sc2 = (idx & 31) * 2;
    ushort2 v; v.x = t[sc2][dr]; v.y = t[sc2 + 1][dr];
    *(ushort2*)&Vt[((size_t)g * HDIM + d0 + dr) * S_LEN + s0 + sc2] = v;
  }
}

// ---------------- causal GQA flash attention: K dbuf + single-V + defer-rescale (r23-proven) ----------------
__global__ __launch_bounds__(256, 3) void attn(
    const ushort* __restrict__ Q, const ushort* __restrict__ K,
    const ushort* __restrict__ Vt, ushort* __restrict__ ctx) {
  __shared__ __align__(16) ushort Ks[2][64 * 128];   // [key][d], chunk(16) ^= row&7
  __shared__ __align__(16) ushort Vs[128 * 64];      // [d][key], chunk(8)  ^= d&7
  const int tid = threadIdx.x;
  const int wid = tid >> 6, lane = tid & 63;
  const int l15 = lane & 15, lg = lane >> 4;
  const int bkv = blockIdx.x;                   // b*NKV + kvh; maps 1:1 to an XCD
  const int b = bkv >> 2, kvh = bkv & 3;
  const int h = kvh * 4 + wid;                  // wave = one q-head of the group
  const int qb = (gridDim.y - 1) - blockIdx.y;  // longest blocks dispatch first
  const int q0 = qb * 16;

  const ushort* Kbase  = K  + ((size_t)b * S_LEN * NKV + kvh) * HDIM;
  const ushort* Vtbase = Vt + (size_t)bkv * HDIM * S_LEN;

  short8 qf[4];
#pragma unroll
  for (int kd = 0; kd < 4; kd++)
    qf[kd] = *(const short8*)&Q[(((size_t)(b * S_LEN + q0 + l15)) * NH + h) * HDIM + kd * 32 + lg * 8];

  auto stageK = [&](int tile, int bufi) {
    const int j0t = tile * 64;
#pragma unroll
    for (int p = 0; p < 4; ++p) {
      const int i = wid * 4 + p;                // 0..15
      const int row = i * 4 + (lane >> 4);      // key row 0..63
      const int cs  = (lane & 15) ^ (row & 7);
      load_lds16(Kbase + (size_t)(j0t + row) * (NKV * HDIM) + cs * 8,
                 &Ks[bufi][i * 512]);
    }
  };
  auto stageV = [&](int tile) {
    const int j0t = tile * 64;
#pragma unroll
    for (int p = 0; p < 4; ++p) {
      const int i = wid * 4 + p;                // 0..15
      const int d  = i * 8 + (lane >> 3);       // d row 0..127
      const int cs = (lane & 7) ^ (d & 7);
      load_lds16(Vtbase + (size_t)d * S_LEN + j0t + cs * 8,
                 &Vs[i * 512]);
    }
  };

  f32x4 o2[8] = {};
  float m_run = -3e30f, l_run = 0.f;
  const int ntile = q0 / 64 + 1;
  const int qrow = q0 + l15;

  stageK(0, 0);
  __syncthreads();
  int buf = 0;
  for (int jt = 0; jt < ntile; ++jt) {
    const int j0 = jt * 64;
    if (jt + 1 < ntile) stageK(jt + 1, buf ^ 1);
    stageV(jt);                                  // lands under QK^T+softmax

    f32x4 sa[4] = {};
#pragma unroll
    for (int t = 0; t < 4; ++t) {
      const int r = t * 16 + l15;
#pragma unroll
      for (int kd = 0; kd < 4; ++kd) {
        short8 kf = *(const short8*)&Ks[buf][r * 128 + (((kd * 4 + lg) ^ (r & 7)) * 8)];
        sa[t] = __builtin_amdgcn_mfma_f32_16x16x32_bf16(kf, qf[kd], sa[t], 0, 0, 0);
      }
    }

    float pv[4][4];
    float mx = -3e30f;
#pragma unroll
    for (int t = 0; t < 4; ++t)
#pragma unroll
      for (int r = 0; r < 4; ++r) {
        float v = sa[t][r];
        if (j0 + t * 16 + lg * 4 + r > qrow) v = -3e30f;   // causal mask
        pv[t][r] = v;
        mx = fmaxf(mx, v);
      }
    mx = fmaxf(mx, __shfl_xor(mx, 16));
    mx = fmaxf(mx, __shfl_xor(mx, 32));
    // T13 defer-rescale: skip the O-wide rescale while max growth <= 8
    if (!__all(mx <= m_run + 8.f)) {
      const float mnew = fmaxf(m_run, mx);
      const float fac = fexp2(m_run - mnew);
      m_run = mnew;
      l_run *= fac;
#pragma unroll
      for (int dt = 0; dt < 8; ++dt)
#pragma unroll
        for (int r = 0; r < 4; ++r) o2[dt][r] *= fac;
    }
    float sum = 0.f;
#pragma unroll
    for (int t = 0; t < 4; ++t)
#pragma unroll
      for (int r = 0; r < 4; ++r) {
        float p = fexp2(pv[t][r] - m_run);       // <= 2^8
        pv[t][r] = p;
        sum += p;
      }
    sum += __shfl_xor(sum, 16);
    sum += __shfl_xor(sum, 32);
    l_run += sum;

    unsigned pk[4][2];
#pragma unroll
    for (int t = 0; t < 4; ++t)
#pragma unroll
      for (int p = 0; p < 2; ++p)
        pk[t][p] = cvt_pk_bf16(pv[t][2 * p], pv[t][2 * p + 1]);

    union U8 { unsigned u[4]; short8 s; } pfk[2];
#pragma unroll
    for (int ks = 0; ks < 2; ++ks)
#pragma unroll
      for (int j = 0; j < 4; ++j) {
        const int src = ((lg & 1) * 2 + (j >> 1)) * 16 + l15;
        unsigned v0 = __shfl((int)pk[ks * 2][j & 1], src);
        unsigned v1 = __shfl((int)pk[ks * 2 + 1][j & 1], src);
        pfk[ks].u[j] = (lg >= 2) ? v1 : v0;
      }

    __syncthreads();   // V(jt) writes visible to all waves before PV reads

#pragma unroll
    for (int dt = 0; dt < 8; ++dt) {
      const int d = dt * 16 + l15;
#pragma unroll
      for (int ks = 0; ks < 2; ++ks) {
        short8 vf = *(const short8*)&Vs[d * 64 + (((ks * 4 + lg) ^ (d & 7)) * 8)];
        o2[dt] = __builtin_amdgcn_mfma_f32_16x16x32_bf16(vf, pfk[ks].s, o2[dt], 0, 0, 0);
      }
    }

    __syncthreads();   // V reads done before next stageV; Ks[buf^1] landed
    buf ^= 1;
  }

  const float inv_l = 1.f / l_run;
  const size_t obase = (((size_t)(b * S_LEN + q0 + l15)) * NH + h) * HDIM;
#pragma unroll
  for (int dt = 0; dt < 8; ++dt) {
    ushort4 w;
    w.x = f2bf(o2[dt][0] * inv_l);
    w.y = f2bf(o2[dt][1] * inv_l);
    w.z = f2bf(o2[dt][2] * inv_l);
    w.w = f2bf(o2[dt][3] * inv_l);
    *(ushort4*)&ctx[obase + dt * 16 + lg * 4] = w;
  }
}

// ---------------- launcher ----------------
extern "C" void kernel_launch(void* const* d_in, const int* in_sizes, int n_in,
                              void* d_out, int out_size, void* d_ws, size_t ws_size,
                              hipStream_t stream) {
  const float* x      = (const float*)d_in[0];
  const float* w_in   = (const float*)d_in[1];
  const float* b_in   = (const float*)d_in[2];
  const float* conv_w = (const float*)d_in[3];
  const float* conv_b = (const float*)d_in[4];
  const float* w_out  = (const float*)d_in[5];
  const float* b_out  = (const float*)d_in[6];
  float* out = (float*)d_out;

  char* ws = (char*)d_ws;
  size_t off = 0;
  ushort* xbf  = (ushort*)(ws + off); off += (size_t)4096 * 2048 * 2;  // x bf16; later reused as ctx
  ushort* wibf = (ushort*)(ws + off); off += (size_t)3072 * 2048 * 2;
  ushort* wobf = (ushort*)(ws + off); off += (size_t)2048 * 2048 * 2;
  ushort* qkv  = (ushort*)(ws + off); off += (size_t)4096 * 3072 * 2;  // bf16; dead after conv_rope
  ushort* Qb   = (ushort*)(ws + off); off += (size_t)4096 * 16 * 128 * 2;
  ushort* Kb   = (ushort*)(ws + off); off += (size_t)4096 * 4 * 128 * 2;
  ushort* Vb   = (ushort*)(ws + off); off += (size_t)4096 * 4 * 128 * 2;
  float*  cosT = (float*)(ws + off);  off += (size_t)2048 * 64 * 4;
  float*  sinT = (float*)(ws + off);  off += (size_t)2048 * 64 * 4;
  float*  cwT  = (float*)(ws + off);  off += (size_t)4 * QKVD * 4;     // transposed conv weights
  ushort* Vtb  = (ushort*)qkv;        // alias: transposed V lives in dead qkv buffer (8 MB)

  // 18432 cast + 512 rope + 48 cwT = 18992 blocks, one launch
  prep<<<18992, 256, 0, stream>>>(x, w_in, w_out, conv_w,
                                  xbf, wibf, wobf, cosT, sinT, cwT);

  gemmA<true><<<256, 512, 0, stream>>>(xbf, wibf, b_in, qkv, 4096, 3072, 2048);
  conv_rope<<<1024, 448, 0, stream>>>(qkv, cwT, conv_b, cosT, sinT, Qb, Kb, Vb);
  transpose_v<<<dim3(32, 2, 8), 256, 0, stream>>>(Vb, Vtb);
  attn<<<dim3(8, 128), 256, 0, stream>>>(Qb, Kb, Vtb, xbf);
  gemm128<false><<<512, 256, 0, stream>>>(xbf, wobf, b_out, out, 4096, 2048, 2048);
}